// Round 1
// baseline (3108.446 us; speedup 1.0000x reference)
//
#include <hip/hip_runtime.h>
#include <math.h>

#define B_  32
#define T_  512
#define S_  256
#define D_  256
#define H_  8
#define HD_ 32
#define FF_ 1024
#define ED_ 768
#define L_  4
#define BT_ (B_*T_)   // 16384
#define BS_ (B_*S_)   // 8192

__device__ __forceinline__ float gelu_f(float v) {
  return 0.5f * v * (1.f + erff(v * 0.7071067811865476f));
}

// ---------------- embed: x = tgt*W_emb + b_emb + pos_encoding ----------------
__global__ __launch_bounds__(256)
void embed_kernel(const float* __restrict__ tgt, const float* __restrict__ Wemb,
                  const float* __restrict__ bemb, float* __restrict__ x) {
  int i = blockIdx.x * 256 + threadIdx.x;       // over B*T*D, exact multiple
  int d  = i & (D_ - 1);
  int bt = i >> 8;                               // D_==256
  int t  = bt & (T_ - 1);                        // T_==512
  int p  = d >> 1;
  float div = expf((float)(2 * p) * (-9.210340371976184f / (float)D_)); // -ln(10000)/D
  float arg = (float)t * div;
  float pe = (d & 1) ? cosf(arg) : sinf(arg);
  x[i] = tgt[bt] * Wemb[d] + bemb[d] + pe;
}

// ---------------- generic fp32 GEMM: C = A(MxK) @ W(KxN) + bias, opt GELU ----
// block 256 threads, tile 64x64, K-step 16, 4x4 microtile.
// Requires M%64==0, N%64==0, K%16==0 (true for all call sites).
template<int ACT>
__global__ __launch_bounds__(256, 2)
void gemm_kernel(const float* __restrict__ A, const float* __restrict__ W,
                 const float* __restrict__ bias, float* __restrict__ C,
                 int M, int N, int K) {
  __shared__ float As[16][68];   // [k][m], pad->stride 68 keeps float4 alignment
  __shared__ float Ws[16][68];   // [k][n]
  const int tid = threadIdx.x;
  const int tx = tid & 15;                // n quad
  const int ty = tid >> 4;                // m quad
  const int bm = blockIdx.y * 64;
  const int bn = blockIdx.x * 64;
  const int arow = tid >> 2, ak = (tid & 3) * 4;     // A: 64 rows x 4-float k chunks
  const int wrow = tid >> 4, wn = (tid & 15) * 4;    // W: 16 k-rows x 4-float n chunks
  const float* Aptr = A + (size_t)(bm + arow) * K + ak;
  const float* Wptr = W + (size_t)wrow * N + bn + wn;

  float acc[4][4] = {};
  for (int k0 = 0; k0 < K; k0 += 16) {
    float4 av = *(const float4*)(Aptr + k0);
    float4 wv = *(const float4*)(Wptr + (size_t)k0 * N);
    As[ak + 0][arow] = av.x;
    As[ak + 1][arow] = av.y;
    As[ak + 2][arow] = av.z;
    As[ak + 3][arow] = av.w;
    *(float4*)&Ws[wrow][wn] = wv;
    __syncthreads();
#pragma unroll
    for (int kk = 0; kk < 16; ++kk) {
      float4 a = *(const float4*)&As[kk][ty * 4];
      float4 w = *(const float4*)&Ws[kk][tx * 4];
      acc[0][0] = fmaf(a.x, w.x, acc[0][0]);
      acc[0][1] = fmaf(a.x, w.y, acc[0][1]);
      acc[0][2] = fmaf(a.x, w.z, acc[0][2]);
      acc[0][3] = fmaf(a.x, w.w, acc[0][3]);
      acc[1][0] = fmaf(a.y, w.x, acc[1][0]);
      acc[1][1] = fmaf(a.y, w.y, acc[1][1]);
      acc[1][2] = fmaf(a.y, w.z, acc[1][2]);
      acc[1][3] = fmaf(a.y, w.w, acc[1][3]);
      acc[2][0] = fmaf(a.z, w.x, acc[2][0]);
      acc[2][1] = fmaf(a.z, w.y, acc[2][1]);
      acc[2][2] = fmaf(a.z, w.z, acc[2][2]);
      acc[2][3] = fmaf(a.z, w.w, acc[2][3]);
      acc[3][0] = fmaf(a.w, w.x, acc[3][0]);
      acc[3][1] = fmaf(a.w, w.y, acc[3][1]);
      acc[3][2] = fmaf(a.w, w.z, acc[3][2]);
      acc[3][3] = fmaf(a.w, w.w, acc[3][3]);
    }
    __syncthreads();
  }
  const float4 bv = *(const float4*)&bias[bn + tx * 4];
#pragma unroll
  for (int i = 0; i < 4; ++i) {
    float4 o;
    o.x = acc[i][0] + bv.x;
    o.y = acc[i][1] + bv.y;
    o.z = acc[i][2] + bv.z;
    o.w = acc[i][3] + bv.w;
    if (ACT == 1) { o.x = gelu_f(o.x); o.y = gelu_f(o.y); o.z = gelu_f(o.z); o.w = gelu_f(o.w); }
    *(float4*)&C[(size_t)(bm + ty * 4 + i) * N + bn + tx * 4] = o;
  }
}

// ---------------- attention: one query row per thread, online softmax --------
// Q,O: (B, T_, D_) head slice at h*HD_ ; K,V: (B, S, D_). grid=(B*H, T_/256)
template<bool CAUSAL>
__global__ __launch_bounds__(256, 2)
void attn_kernel(const float* __restrict__ Q, const float* __restrict__ K,
                 const float* __restrict__ V, float* __restrict__ O, int S) {
  const int b = blockIdx.x >> 3;   // / H_
  const int h = blockIdx.x & 7;
  const int t = blockIdx.y * 256 + threadIdx.x;
  __shared__ float Ks[32][36];
  __shared__ float Vs[32][36];

  const float* Qp = Q + ((size_t)(b * T_ + t)) * D_ + h * HD_;
  float q[HD_];
#pragma unroll
  for (int d4 = 0; d4 < HD_ / 4; ++d4) {
    float4 qq = *(const float4*)(Qp + d4 * 4);
    q[d4 * 4 + 0] = qq.x * 0.17677669529663689f;   // 1/sqrt(HD)
    q[d4 * 4 + 1] = qq.y * 0.17677669529663689f;
    q[d4 * 4 + 2] = qq.z * 0.17677669529663689f;
    q[d4 * 4 + 3] = qq.w * 0.17677669529663689f;
  }
  float m = -3.0e38f, l = 0.f;
  float o[HD_] = {};
  const int slim = CAUSAL ? min(S, ((int)blockIdx.y + 1) * 256) : S;
  const int krow = threadIdx.x >> 3, kc = (threadIdx.x & 7) * 4;

  for (int s0 = 0; s0 < slim; s0 += 32) {
    const size_t kvbase = ((size_t)(b * S + s0 + krow)) * D_ + h * HD_ + kc;
    float4 kv = *(const float4*)(K + kvbase);
    float4 vv = *(const float4*)(V + kvbase);
    *(float4*)&Ks[krow][kc] = kv;
    *(float4*)&Vs[krow][kc] = vv;
    __syncthreads();

    float sreg[32];
    float tmax = -3.0e38f;
#pragma unroll
    for (int j = 0; j < 32; ++j) {
      float s = 0.f;
#pragma unroll
      for (int d = 0; d < HD_; ++d) s = fmaf(q[d], Ks[j][d], s);
      if (CAUSAL && (s0 + j) > t) s -= 1e9f;   // additive mask, matches reference
      sreg[j] = s;
      tmax = fmaxf(tmax, s);
    }
    float mnew = fmaxf(m, tmax);
    float corr = __expf(m - mnew);
    l *= corr;
#pragma unroll
    for (int d = 0; d < HD_; ++d) o[d] *= corr;
#pragma unroll
    for (int j = 0; j < 32; ++j) {
      float p = __expf(sreg[j] - mnew);
      l += p;
#pragma unroll
      for (int d = 0; d < HD_; ++d) o[d] = fmaf(p, Vs[j][d], o[d]);
    }
    m = mnew;
    __syncthreads();
  }
  float inv = 1.f / l;
  float* Op = O + ((size_t)(b * T_ + t)) * D_ + h * HD_;
#pragma unroll
  for (int d4 = 0; d4 < HD_ / 4; ++d4) {
    float4 ov;
    ov.x = o[d4 * 4 + 0] * inv;
    ov.y = o[d4 * 4 + 1] * inv;
    ov.z = o[d4 * 4 + 2] * inv;
    ov.w = o[d4 * 4 + 3] * inv;
    *(float4*)(Op + d4 * 4) = ov;
  }
}

// ---------------- fused residual add + LayerNorm (in-place on x) -------------
// one wave per 256-elem row; block = 4 waves
__global__ __launch_bounds__(256)
void add_ln_kernel(float* __restrict__ x, const float* __restrict__ y,
                   const float* __restrict__ g, const float* __restrict__ bta) {
  const int row = blockIdx.x * 4 + (threadIdx.x >> 6);
  const int lane = threadIdx.x & 63;
  const size_t base = (size_t)row * D_ + lane * 4;
  float4 xv = *(const float4*)&x[base];
  float4 yv = *(const float4*)&y[base];
  float v0 = xv.x + yv.x, v1 = xv.y + yv.y, v2 = xv.z + yv.z, v3 = xv.w + yv.w;
  float sum = v0 + v1 + v2 + v3;
  float sq  = v0 * v0 + v1 * v1 + v2 * v2 + v3 * v3;
#pragma unroll
  for (int off = 32; off; off >>= 1) {
    sum += __shfl_xor(sum, off);
    sq  += __shfl_xor(sq, off);
  }
  float mean = sum * (1.f / D_);
  float var  = sq * (1.f / D_) - mean * mean;
  float rstd = rsqrtf(fmaxf(var, 0.f) + 1e-5f);
  const int c = lane * 4;
  float4 gv = *(const float4*)&g[c];
  float4 bv = *(const float4*)&bta[c];
  float4 ov;
  ov.x = (v0 - mean) * rstd * gv.x + bv.x;
  ov.y = (v1 - mean) * rstd * gv.y + bv.y;
  ov.z = (v2 - mean) * rstd * gv.z + bv.z;
  ov.w = (v3 - mean) * rstd * gv.w + bv.w;
  *(float4*)&x[base] = ov;
}

// ---------------- final matvec: out = h(BTx128) @ Wp2(128x1) + bp2 -----------
__global__ __launch_bounds__(256)
void head2_kernel(const float* __restrict__ hb, const float* __restrict__ w,
                  const float* __restrict__ bias, float* __restrict__ out) {
  const int row = blockIdx.x * 4 + (threadIdx.x >> 6);
  const int lane = threadIdx.x & 63;
  float a = hb[(size_t)row * 128 + lane] * w[lane]
          + hb[(size_t)row * 128 + 64 + lane] * w[64 + lane];
#pragma unroll
  for (int off = 32; off; off >>= 1) a += __shfl_xor(a, off);
  if (lane == 0) out[row] = a + bias[0];
}

extern "C" void kernel_launch(void* const* d_in, const int* in_sizes, int n_in,
                              void* d_out, int out_size, void* d_ws, size_t ws_size,
                              hipStream_t stream) {
  const float* tgt    = (const float*)d_in[0];
  const float* memory = (const float*)d_in[1];
  const float* W_emb  = (const float*)d_in[2];
  const float* b_emb  = (const float*)d_in[3];
  const float* W_enc  = (const float*)d_in[4];
  const float* b_enc  = (const float*)d_in[5];
  const float* Wq_s = (const float*)d_in[6];  const float* bq_s = (const float*)d_in[7];
  const float* Wk_s = (const float*)d_in[8];  const float* bk_s = (const float*)d_in[9];
  const float* Wv_s = (const float*)d_in[10]; const float* bv_s = (const float*)d_in[11];
  const float* Wo_s = (const float*)d_in[12]; const float* bo_s = (const float*)d_in[13];
  const float* Wq_c = (const float*)d_in[14]; const float* bq_c = (const float*)d_in[15];
  const float* Wk_c = (const float*)d_in[16]; const float* bk_c = (const float*)d_in[17];
  const float* Wv_c = (const float*)d_in[18]; const float* bv_c = (const float*)d_in[19];
  const float* Wo_c = (const float*)d_in[20]; const float* bo_c = (const float*)d_in[21];
  const float* g1  = (const float*)d_in[22]; const float* be1 = (const float*)d_in[23];
  const float* g2  = (const float*)d_in[24]; const float* be2 = (const float*)d_in[25];
  const float* g3  = (const float*)d_in[26]; const float* be3 = (const float*)d_in[27];
  const float* Wf1 = (const float*)d_in[28]; const float* bf1 = (const float*)d_in[29];
  const float* Wf2 = (const float*)d_in[30]; const float* bf2 = (const float*)d_in[31];
  const float* Wp1 = (const float*)d_in[32]; const float* bp1 = (const float*)d_in[33];
  const float* Wp2 = (const float*)d_in[34]; const float* bp2 = (const float*)d_in[35];

  // workspace layout (floats): x | mem | y | scratch(q,k,v,ao == ff region)
  float* x   = (float*)d_ws;                   // BT*D      = 4,194,304
  float* mem = x + (size_t)BT_ * D_;           // BS*D      = 2,097,152
  float* y   = mem + (size_t)BS_ * D_;         // BT*D      = 4,194,304
  float* scr = y + (size_t)BT_ * D_;           // BT*FF     = 16,777,216
  float* q  = scr;
  float* k  = scr + (size_t)BT_ * D_;
  float* v  = scr + 2 * (size_t)BT_ * D_;
  float* ao = scr + 3 * (size_t)BT_ * D_;
  float* ff = scr;

  dim3 blk(256);
  const dim3 gP(D_ / 64, BT_ / 64);    // 16384 x 256 projections
  const dim3 gM(D_ / 64, BS_ / 64);    // 8192 x 256 projections

  embed_kernel<<<BT_ * D_ / 256, blk, 0, stream>>>(tgt, W_emb, b_emb, x);
  gemm_kernel<0><<<gM, blk, 0, stream>>>(memory, W_enc, b_enc, mem, BS_, D_, ED_);

  for (int i = 0; i < L_; ++i) {
    // ---- self attention ----
    gemm_kernel<0><<<gP, blk, 0, stream>>>(x, Wq_s + (size_t)i * D_ * D_, bq_s + i * D_, q, BT_, D_, D_);
    gemm_kernel<0><<<gP, blk, 0, stream>>>(x, Wk_s + (size_t)i * D_ * D_, bk_s + i * D_, k, BT_, D_, D_);
    gemm_kernel<0><<<gP, blk, 0, stream>>>(x, Wv_s + (size_t)i * D_ * D_, bv_s + i * D_, v, BT_, D_, D_);
    attn_kernel<true><<<dim3(B_ * H_, T_ / 256), blk, 0, stream>>>(q, k, v, ao, T_);
    gemm_kernel<0><<<gP, blk, 0, stream>>>(ao, Wo_s + (size_t)i * D_ * D_, bo_s + i * D_, y, BT_, D_, D_);
    add_ln_kernel<<<BT_ / 4, blk, 0, stream>>>(x, y, g1 + i * D_, be1 + i * D_);
    // ---- cross attention ----
    gemm_kernel<0><<<gP, blk, 0, stream>>>(x, Wq_c + (size_t)i * D_ * D_, bq_c + i * D_, q, BT_, D_, D_);
    gemm_kernel<0><<<gM, blk, 0, stream>>>(mem, Wk_c + (size_t)i * D_ * D_, bk_c + i * D_, k, BS_, D_, D_);
    gemm_kernel<0><<<gM, blk, 0, stream>>>(mem, Wv_c + (size_t)i * D_ * D_, bv_c + i * D_, v, BS_, D_, D_);
    attn_kernel<false><<<dim3(B_ * H_, T_ / 256), blk, 0, stream>>>(q, k, v, ao, S_);
    gemm_kernel<0><<<gP, blk, 0, stream>>>(ao, Wo_c + (size_t)i * D_ * D_, bo_c + i * D_, y, BT_, D_, D_);
    add_ln_kernel<<<BT_ / 4, blk, 0, stream>>>(x, y, g2 + i * D_, be2 + i * D_);
    // ---- feed-forward ----
    gemm_kernel<1><<<dim3(FF_ / 64, BT_ / 64), blk, 0, stream>>>(x, Wf1 + (size_t)i * D_ * FF_, bf1 + i * FF_, ff, BT_, FF_, D_);
    gemm_kernel<0><<<dim3(D_ / 64, BT_ / 64), blk, 0, stream>>>(ff, Wf2 + (size_t)i * FF_ * D_, bf2 + i * D_, y, BT_, D_, FF_);
    add_ln_kernel<<<BT_ / 4, blk, 0, stream>>>(x, y, g3 + i * D_, be3 + i * D_);
  }
  // ---- head ----
  gemm_kernel<1><<<dim3(128 / 64, BT_ / 64), blk, 0, stream>>>(x, Wp1, bp1, y, BT_, 128, D_);
  head2_kernel<<<BT_ / 4, blk, 0, stream>>>(y, Wp2, bp2, (float*)d_out);
}

// Round 2
// 1829.648 us; speedup vs baseline: 1.6989x; 1.6989x over previous
//
#include <hip/hip_runtime.h>
#include <math.h>

#define B_  32
#define T_  512
#define S_  256
#define D_  256
#define H_  8
#define HD_ 32
#define FF_ 1024
#define ED_ 768
#define L_  4
#define BT_ (B_*T_)   // 16384
#define BS_ (B_*S_)   // 8192

typedef __bf16 bf16x8_t __attribute__((ext_vector_type(8)));
typedef __bf16 bf16x4_t __attribute__((ext_vector_type(4)));
typedef float  f32x4_t  __attribute__((ext_vector_type(4)));

__device__ __forceinline__ float gelu_f(float v) {
  return 0.5f * v * (1.f + erff(v * 0.7071067811865476f));
}

// ---------------- embed: x = tgt*W_emb + b_emb + pos_encoding ----------------
__global__ __launch_bounds__(256)
void embed_kernel(const float* __restrict__ tgt, const float* __restrict__ Wemb,
                  const float* __restrict__ bemb, float* __restrict__ x) {
  int i = blockIdx.x * 256 + threadIdx.x;
  int d  = i & (D_ - 1);
  int bt = i >> 8;
  int t  = bt & (T_ - 1);
  int p  = d >> 1;
  float div = expf((float)(2 * p) * (-9.210340371976184f / (float)D_));
  float arg = (float)t * div;
  float pe = (d & 1) ? cosf(arg) : sinf(arg);
  x[i] = tgt[bt] * Wemb[d] + bemb[d] + pe;
}

// ------------- weight pre-pass: transpose [K][N] fp32 -> [N][K] bf16 ---------
struct TD { const float* src; size_t dst; int K, N, nb; };
struct TDs { TD d[12]; };

__global__ __launch_bounds__(256)
void transpose_cvt_kernel(TDs a, __bf16* __restrict__ wt) {
  __shared__ float tile[32][33];
  TD t = a.d[blockIdx.y];
  const int kt = t.K >> 5, nt = t.N >> 5;
  const int per = kt * nt, tot = per * t.nb;
  const int id = blockIdx.x;
  if (id >= tot) return;
  const int b = id / per;
  const int r2 = id - b * per;
  const int kti = r2 / nt;
  const int nti = r2 - kti * nt;
  const int c = threadIdx.x & 31, r0 = threadIdx.x >> 5;
  const float* src = t.src + (size_t)b * t.K * t.N;
  __bf16* dst = wt + t.dst + (size_t)b * t.K * t.N;
#pragma unroll
  for (int j = 0; j < 4; ++j) {
    int rr = r0 + j * 8;
    tile[rr][c] = src[(size_t)(kti * 32 + rr) * t.N + nti * 32 + c];
  }
  __syncthreads();
#pragma unroll
  for (int j = 0; j < 4; ++j) {
    int rr = r0 + j * 8;
    dst[(size_t)(nti * 32 + rr) * t.K + kti * 32 + c] = (__bf16)tile[c][rr];
  }
}

// ---------------- bf16 MFMA GEMM: C = A(MxK,f32) @ Wt(NxK,bf16)^T + bias -----
// block 256 thr = 4 waves (2x2), tile 128x64, BK=32, per-wave 4x2 16x16 frags.
template<int ACT>
__global__ __launch_bounds__(256, 2)
void gemm_mfma(const float* __restrict__ A, const __bf16* __restrict__ Bt,
               const float* __restrict__ bias, float* __restrict__ C,
               int M, int N, int K) {
  __shared__ __bf16 As[128][40];   // stride 40 bf16 = 80B -> bank stride 20, ~2-way max
  __shared__ __bf16 Bs[64][40];
  const int tid  = threadIdx.x;
  const int lane = tid & 63;
  const int wv   = tid >> 6;
  const int wm = (wv & 1) * 64;
  const int wn = (wv >> 1) * 32;
  const int ln15 = lane & 15;
  const int kgrp = lane >> 4;
  const int bm = blockIdx.y * 128;
  const int bn = blockIdx.x * 64;

  // A staging map: row = rep*32 + (tid>>3), ch = tid&7 (float4 along k)
  const int a_row = tid >> 3, a_ch = (tid & 7) * 4;
  const float* a_base = A + (size_t)(bm + a_row) * K + a_ch;
  // B staging map: n = tid>>2, kc = (tid&3)*8 (bf16x8 along k)
  const int b_n = tid >> 2, b_kc = (tid & 3) * 8;
  const __bf16* b_base = Bt + (size_t)(bn + b_n) * K + b_kc;

  f32x4_t acc[4][2];
#pragma unroll
  for (int mi = 0; mi < 4; ++mi)
#pragma unroll
    for (int ni = 0; ni < 2; ++ni) acc[mi][ni] = (f32x4_t){0.f, 0.f, 0.f, 0.f};

  for (int k0 = 0; k0 < K; k0 += 32) {
#pragma unroll
    for (int rep = 0; rep < 4; ++rep) {
      float4 av = *(const float4*)(a_base + (size_t)rep * 32 * K + k0);
      bf16x4_t cv;
      cv[0] = (__bf16)av.x; cv[1] = (__bf16)av.y;
      cv[2] = (__bf16)av.z; cv[3] = (__bf16)av.w;
      *(bf16x4_t*)&As[a_row + rep * 32][a_ch] = cv;
    }
    *(bf16x8_t*)&Bs[b_n][b_kc] = *(const bf16x8_t*)(b_base + k0);
    __syncthreads();

    bf16x8_t bfrag[2];
#pragma unroll
    for (int ni = 0; ni < 2; ++ni)
      bfrag[ni] = *(const bf16x8_t*)&Bs[wn + ni * 16 + ln15][kgrp * 8];
#pragma unroll
    for (int mi = 0; mi < 4; ++mi) {
      bf16x8_t afrag = *(const bf16x8_t*)&As[wm + mi * 16 + ln15][kgrp * 8];
      acc[mi][0] = __builtin_amdgcn_mfma_f32_16x16x32_bf16(afrag, bfrag[0], acc[mi][0], 0, 0, 0);
      acc[mi][1] = __builtin_amdgcn_mfma_f32_16x16x32_bf16(afrag, bfrag[1], acc[mi][1], 0, 0, 0);
    }
    __syncthreads();
  }

#pragma unroll
  for (int mi = 0; mi < 4; ++mi) {
#pragma unroll
    for (int ni = 0; ni < 2; ++ni) {
      const int ocol = bn + wn + ni * 16 + ln15;
      const float bv = bias[ocol];
      const int orow0 = bm + wm + mi * 16 + kgrp * 4;
#pragma unroll
      for (int r = 0; r < 4; ++r) {
        float o = acc[mi][ni][r] + bv;
        if (ACT == 1) o = gelu_f(o);
        C[(size_t)(orow0 + r) * N + ocol] = o;
      }
    }
  }
}

// ---------------- attention: one query row per thread, online softmax --------
template<bool CAUSAL>
__global__ __launch_bounds__(256, 2)
void attn_kernel(const float* __restrict__ Q, const float* __restrict__ K,
                 const float* __restrict__ V, float* __restrict__ O, int S) {
  const int b = blockIdx.x >> 3;
  const int h = blockIdx.x & 7;
  const int t = blockIdx.y * 256 + threadIdx.x;
  __shared__ float Ks[32][36];
  __shared__ float Vs[32][36];

  const float* Qp = Q + ((size_t)(b * T_ + t)) * D_ + h * HD_;
  float q[HD_];
#pragma unroll
  for (int d4 = 0; d4 < HD_ / 4; ++d4) {
    float4 qq = *(const float4*)(Qp + d4 * 4);
    q[d4 * 4 + 0] = qq.x * 0.17677669529663689f;
    q[d4 * 4 + 1] = qq.y * 0.17677669529663689f;
    q[d4 * 4 + 2] = qq.z * 0.17677669529663689f;
    q[d4 * 4 + 3] = qq.w * 0.17677669529663689f;
  }
  float m = -3.0e38f, l = 0.f;
  float o[HD_] = {};
  const int slim = CAUSAL ? min(S, ((int)blockIdx.y + 1) * 256) : S;
  const int krow = threadIdx.x >> 3, kc = (threadIdx.x & 7) * 4;

  for (int s0 = 0; s0 < slim; s0 += 32) {
    const size_t kvbase = ((size_t)(b * S + s0 + krow)) * D_ + h * HD_ + kc;
    float4 kv = *(const float4*)(K + kvbase);
    float4 vv = *(const float4*)(V + kvbase);
    *(float4*)&Ks[krow][kc] = kv;
    *(float4*)&Vs[krow][kc] = vv;
    __syncthreads();

    float sreg[32];
    float tmax = -3.0e38f;
#pragma unroll
    for (int j = 0; j < 32; ++j) {
      float s = 0.f;
#pragma unroll
      for (int d = 0; d < HD_; ++d) s = fmaf(q[d], Ks[j][d], s);
      if (CAUSAL && (s0 + j) > t) s -= 1e9f;
      sreg[j] = s;
      tmax = fmaxf(tmax, s);
    }
    float mnew = fmaxf(m, tmax);
    float corr = __expf(m - mnew);
    l *= corr;
#pragma unroll
    for (int d = 0; d < HD_; ++d) o[d] *= corr;
#pragma unroll
    for (int j = 0; j < 32; ++j) {
      float p = __expf(sreg[j] - mnew);
      l += p;
#pragma unroll
      for (int d = 0; d < HD_; ++d) o[d] = fmaf(p, Vs[j][d], o[d]);
    }
    m = mnew;
    __syncthreads();
  }
  float inv = 1.f / l;
  float* Op = O + ((size_t)(b * T_ + t)) * D_ + h * HD_;
#pragma unroll
  for (int d4 = 0; d4 < HD_ / 4; ++d4) {
    float4 ov;
    ov.x = o[d4 * 4 + 0] * inv;
    ov.y = o[d4 * 4 + 1] * inv;
    ov.z = o[d4 * 4 + 2] * inv;
    ov.w = o[d4 * 4 + 3] * inv;
    *(float4*)(Op + d4 * 4) = ov;
  }
}

// ---------------- fused residual add + LayerNorm (in-place on x) -------------
__global__ __launch_bounds__(256)
void add_ln_kernel(float* __restrict__ x, const float* __restrict__ y,
                   const float* __restrict__ g, const float* __restrict__ bta) {
  const int row = blockIdx.x * 4 + (threadIdx.x >> 6);
  const int lane = threadIdx.x & 63;
  const size_t base = (size_t)row * D_ + lane * 4;
  float4 xv = *(const float4*)&x[base];
  float4 yv = *(const float4*)&y[base];
  float v0 = xv.x + yv.x, v1 = xv.y + yv.y, v2 = xv.z + yv.z, v3 = xv.w + yv.w;
  float sum = v0 + v1 + v2 + v3;
  float sq  = v0 * v0 + v1 * v1 + v2 * v2 + v3 * v3;
#pragma unroll
  for (int off = 32; off; off >>= 1) {
    sum += __shfl_xor(sum, off);
    sq  += __shfl_xor(sq, off);
  }
  float mean = sum * (1.f / D_);
  float var  = sq * (1.f / D_) - mean * mean;
  float rstd = rsqrtf(fmaxf(var, 0.f) + 1e-5f);
  const int c = lane * 4;
  float4 gv = *(const float4*)&g[c];
  float4 bv = *(const float4*)&bta[c];
  float4 ov;
  ov.x = (v0 - mean) * rstd * gv.x + bv.x;
  ov.y = (v1 - mean) * rstd * gv.y + bv.y;
  ov.z = (v2 - mean) * rstd * gv.z + bv.z;
  ov.w = (v3 - mean) * rstd * gv.w + bv.w;
  *(float4*)&x[base] = ov;
}

// ---------------- final matvec: out = h(BTx128) @ Wp2(128x1) + bp2 -----------
__global__ __launch_bounds__(256)
void head2_kernel(const float* __restrict__ hb, const float* __restrict__ w,
                  const float* __restrict__ bias, float* __restrict__ out) {
  const int row = blockIdx.x * 4 + (threadIdx.x >> 6);
  const int lane = threadIdx.x & 63;
  float a = hb[(size_t)row * 128 + lane] * w[lane]
          + hb[(size_t)row * 128 + 64 + lane] * w[64 + lane];
#pragma unroll
  for (int off = 32; off; off >>= 1) a += __shfl_xor(a, off);
  if (lane == 0) out[row] = a + bias[0];
}

extern "C" void kernel_launch(void* const* d_in, const int* in_sizes, int n_in,
                              void* d_out, int out_size, void* d_ws, size_t ws_size,
                              hipStream_t stream) {
  const float* tgt    = (const float*)d_in[0];
  const float* memory = (const float*)d_in[1];
  const float* W_emb  = (const float*)d_in[2];
  const float* b_emb  = (const float*)d_in[3];
  const float* W_enc  = (const float*)d_in[4];
  const float* b_enc  = (const float*)d_in[5];
  const float* Wq_s = (const float*)d_in[6];  const float* bq_s = (const float*)d_in[7];
  const float* Wk_s = (const float*)d_in[8];  const float* bk_s = (const float*)d_in[9];
  const float* Wv_s = (const float*)d_in[10]; const float* bv_s = (const float*)d_in[11];
  const float* Wo_s = (const float*)d_in[12]; const float* bo_s = (const float*)d_in[13];
  const float* Wq_c = (const float*)d_in[14]; const float* bq_c = (const float*)d_in[15];
  const float* Wk_c = (const float*)d_in[16]; const float* bk_c = (const float*)d_in[17];
  const float* Wv_c = (const float*)d_in[18]; const float* bv_c = (const float*)d_in[19];
  const float* Wo_c = (const float*)d_in[20]; const float* bo_c = (const float*)d_in[21];
  const float* g1  = (const float*)d_in[22]; const float* be1 = (const float*)d_in[23];
  const float* g2  = (const float*)d_in[24]; const float* be2 = (const float*)d_in[25];
  const float* g3  = (const float*)d_in[26]; const float* be3 = (const float*)d_in[27];
  const float* Wf1 = (const float*)d_in[28]; const float* bf1 = (const float*)d_in[29];
  const float* Wf2 = (const float*)d_in[30]; const float* bf2 = (const float*)d_in[31];
  const float* Wp1 = (const float*)d_in[32]; const float* bp1 = (const float*)d_in[33];
  const float* Wp2 = (const float*)d_in[34]; const float* bp2 = (const float*)d_in[35];

  // workspace layout (floats): x | mem | y | scr(q,k,v,ao == ff) | wt(bf16)
  float* x   = (float*)d_ws;                   // 4,194,304
  float* mem = x + (size_t)BT_ * D_;           // 2,097,152
  float* y   = mem + (size_t)BS_ * D_;         // 4,194,304
  float* scr = y + (size_t)BT_ * D_;           // 16,777,216
  float* q  = scr;
  float* k  = scr + (size_t)BT_ * D_;
  float* v  = scr + 2 * (size_t)BT_ * D_;
  float* ao = scr + 3 * (size_t)BT_ * D_;
  float* ff = scr;
  __bf16* wt = (__bf16*)(scr + (size_t)BT_ * FF_);

  // bf16 weight region offsets (elements)
  const size_t o_enc = 0;
  const size_t o_qs = 196608,  o_ks = 458752,  o_vs = 720896,  o_os = 983040;
  const size_t o_qc = 1245184, o_kc = 1507328, o_vc = 1769472, o_oc = 2031616;
  const size_t o_f1 = 2293760, o_f2 = 3342336, o_p1 = 4390912;
  const size_t WSTR = 65536;   // per-layer stride for DxD weights
  const size_t FSTR = 262144;  // per-layer stride for FF weights

  TDs td;
  td.d[0]  = {W_enc, o_enc, ED_, D_, 1};
  td.d[1]  = {Wq_s, o_qs, D_, D_, L_};
  td.d[2]  = {Wk_s, o_ks, D_, D_, L_};
  td.d[3]  = {Wv_s, o_vs, D_, D_, L_};
  td.d[4]  = {Wo_s, o_os, D_, D_, L_};
  td.d[5]  = {Wq_c, o_qc, D_, D_, L_};
  td.d[6]  = {Wk_c, o_kc, D_, D_, L_};
  td.d[7]  = {Wv_c, o_vc, D_, D_, L_};
  td.d[8]  = {Wo_c, o_oc, D_, D_, L_};
  td.d[9]  = {Wf1, o_f1, D_, FF_, L_};
  td.d[10] = {Wf2, o_f2, FF_, D_, L_};
  td.d[11] = {Wp1, o_p1, D_, 128, 1};

  dim3 blk(256);
  transpose_cvt_kernel<<<dim3(1024, 12), blk, 0, stream>>>(td, wt);

  const dim3 gP(D_ / 64, BT_ / 128);    // (4,128) projections on x
  const dim3 gM(D_ / 64, BS_ / 128);    // (4,64)  projections on mem

  embed_kernel<<<BT_ * D_ / 256, blk, 0, stream>>>(tgt, W_emb, b_emb, x);
  gemm_mfma<0><<<gM, blk, 0, stream>>>(memory, wt + o_enc, b_enc, mem, BS_, D_, ED_);

  for (int i = 0; i < L_; ++i) {
    // ---- self attention ----
    gemm_mfma<0><<<gP, blk, 0, stream>>>(x, wt + o_qs + i * WSTR, bq_s + i * D_, q, BT_, D_, D_);
    gemm_mfma<0><<<gP, blk, 0, stream>>>(x, wt + o_ks + i * WSTR, bk_s + i * D_, k, BT_, D_, D_);
    gemm_mfma<0><<<gP, blk, 0, stream>>>(x, wt + o_vs + i * WSTR, bv_s + i * D_, v, BT_, D_, D_);
    attn_kernel<true><<<dim3(B_ * H_, T_ / 256), blk, 0, stream>>>(q, k, v, ao, T_);
    gemm_mfma<0><<<gP, blk, 0, stream>>>(ao, wt + o_os + i * WSTR, bo_s + i * D_, y, BT_, D_, D_);
    add_ln_kernel<<<BT_ / 4, blk, 0, stream>>>(x, y, g1 + i * D_, be1 + i * D_);
    // ---- cross attention ----
    gemm_mfma<0><<<gP, blk, 0, stream>>>(x, wt + o_qc + i * WSTR, bq_c + i * D_, q, BT_, D_, D_);
    gemm_mfma<0><<<gM, blk, 0, stream>>>(mem, wt + o_kc + i * WSTR, bk_c + i * D_, k, BS_, D_, D_);
    gemm_mfma<0><<<gM, blk, 0, stream>>>(mem, wt + o_vc + i * WSTR, bv_c + i * D_, v, BS_, D_, D_);
    attn_kernel<false><<<dim3(B_ * H_, T_ / 256), blk, 0, stream>>>(q, k, v, ao, S_);
    gemm_mfma<0><<<gP, blk, 0, stream>>>(ao, wt + o_oc + i * WSTR, bo_c + i * D_, y, BT_, D_, D_);
    add_ln_kernel<<<BT_ / 4, blk, 0, stream>>>(x, y, g2 + i * D_, be2 + i * D_);
    // ---- feed-forward ----
    gemm_mfma<1><<<dim3(FF_ / 64, BT_ / 128), blk, 0, stream>>>(x, wt + o_f1 + i * FSTR, bf1 + i * FF_, ff, BT_, FF_, D_);
    gemm_mfma<0><<<dim3(D_ / 64, BT_ / 128), blk, 0, stream>>>(ff, wt + o_f2 + i * FSTR, bf2 + i * D_, y, BT_, D_, FF_);
    add_ln_kernel<<<BT_ / 4, blk, 0, stream>>>(x, y, g3 + i * D_, be3 + i * D_);
  }
  // ---- head ----
  gemm_mfma<1><<<dim3(2, BT_ / 128), blk, 0, stream>>>(x, wt + o_p1, bp1, y, BT_, 128, D_);
  head2_kernel<<<BT_ / 4, blk, 0, stream>>>(y, Wp2, bp2, (float*)d_out);
}

// Round 3
// 1110.259 us; speedup vs baseline: 2.7997x; 1.6479x over previous
//
#include <hip/hip_runtime.h>
#include <math.h>

#define B_  32
#define T_  512
#define S_  256
#define D_  256
#define H_  8
#define HD_ 32
#define FF_ 1024
#define ED_ 768
#define L_  4
#define BT_ (B_*T_)   // 16384
#define BS_ (B_*S_)   // 8192

typedef __bf16 bf16x8_t __attribute__((ext_vector_type(8)));
typedef __bf16 bf16x4_t __attribute__((ext_vector_type(4)));
typedef float  f32x4_t  __attribute__((ext_vector_type(4)));

__device__ __forceinline__ float gelu_f(float v) {
  return 0.5f * v * (1.f + erff(v * 0.7071067811865476f));
}

// ---------------- embed: x = tgt*W_emb + b_emb + pos_encoding ----------------
__global__ __launch_bounds__(256)
void embed_kernel(const float* __restrict__ tgt, const float* __restrict__ Wemb,
                  const float* __restrict__ bemb, float* __restrict__ x) {
  int i = blockIdx.x * 256 + threadIdx.x;
  int d  = i & (D_ - 1);
  int bt = i >> 8;
  int t  = bt & (T_ - 1);
  int p  = d >> 1;
  float div = expf((float)(2 * p) * (-9.210340371976184f / (float)D_));
  float arg = (float)t * div;
  float pe = (d & 1) ? cosf(arg) : sinf(arg);
  x[i] = tgt[bt] * Wemb[d] + bemb[d] + pe;
}

// ------------- weight pre-pass: transpose [K][N] fp32 -> [N][K] bf16 ---------
struct TD { const float* src; size_t dst; int K, N, nb; };
struct TDs { TD d[12]; };

__global__ __launch_bounds__(256)
void transpose_cvt_kernel(TDs a, __bf16* __restrict__ wt) {
  __shared__ float tile[32][33];
  TD t = a.d[blockIdx.y];
  const int kt = t.K >> 5, nt = t.N >> 5;
  const int per = kt * nt, tot = per * t.nb;
  const int id = blockIdx.x;
  if (id >= tot) return;
  const int b = id / per;
  const int r2 = id - b * per;
  const int kti = r2 / nt;
  const int nti = r2 - kti * nt;
  const int c = threadIdx.x & 31, r0 = threadIdx.x >> 5;
  const float* src = t.src + (size_t)b * t.K * t.N;
  __bf16* dst = wt + t.dst + (size_t)b * t.K * t.N;
#pragma unroll
  for (int j = 0; j < 4; ++j) {
    int rr = r0 + j * 8;
    tile[rr][c] = src[(size_t)(kti * 32 + rr) * t.N + nti * 32 + c];
  }
  __syncthreads();
#pragma unroll
  for (int j = 0; j < 4; ++j) {
    int rr = r0 + j * 8;
    dst[(size_t)(nti * 32 + rr) * t.K + kti * 32 + c] = (__bf16)tile[c][rr];
  }
}

// ---------------- bf16 MFMA GEMM: C = A(MxK,f32) @ Wt(NxK,bf16)^T + bias -----
// block 256 thr = 4 waves (2x2), tile 128x64, BK=32, per-wave 4x2 16x16 frags.
// OBF=1: store output as bf16 (C cast to __bf16*)
template<int ACT, int OBF>
__global__ __launch_bounds__(256, 2)
void gemm_mfma(const float* __restrict__ A, const __bf16* __restrict__ Bt,
               const float* __restrict__ bias, float* __restrict__ C,
               int M, int N, int K) {
  __shared__ __bf16 As[128][40];
  __shared__ __bf16 Bs[64][40];
  const int tid  = threadIdx.x;
  const int lane = tid & 63;
  const int wv   = tid >> 6;
  const int wm = (wv & 1) * 64;
  const int wn = (wv >> 1) * 32;
  const int ln15 = lane & 15;
  const int kgrp = lane >> 4;
  const int bm = blockIdx.y * 128;
  const int bn = blockIdx.x * 64;

  const int a_row = tid >> 3, a_ch = (tid & 7) * 4;
  const float* a_base = A + (size_t)(bm + a_row) * K + a_ch;
  const int b_n = tid >> 2, b_kc = (tid & 3) * 8;
  const __bf16* b_base = Bt + (size_t)(bn + b_n) * K + b_kc;

  f32x4_t acc[4][2];
#pragma unroll
  for (int mi = 0; mi < 4; ++mi)
#pragma unroll
    for (int ni = 0; ni < 2; ++ni) acc[mi][ni] = (f32x4_t){0.f, 0.f, 0.f, 0.f};

  for (int k0 = 0; k0 < K; k0 += 32) {
#pragma unroll
    for (int rep = 0; rep < 4; ++rep) {
      float4 av = *(const float4*)(a_base + (size_t)rep * 32 * K + k0);
      bf16x4_t cv;
      cv[0] = (__bf16)av.x; cv[1] = (__bf16)av.y;
      cv[2] = (__bf16)av.z; cv[3] = (__bf16)av.w;
      *(bf16x4_t*)&As[a_row + rep * 32][a_ch] = cv;
    }
    *(bf16x8_t*)&Bs[b_n][b_kc] = *(const bf16x8_t*)(b_base + k0);
    __syncthreads();

    bf16x8_t bfrag[2];
#pragma unroll
    for (int ni = 0; ni < 2; ++ni)
      bfrag[ni] = *(const bf16x8_t*)&Bs[wn + ni * 16 + ln15][kgrp * 8];
#pragma unroll
    for (int mi = 0; mi < 4; ++mi) {
      bf16x8_t afrag = *(const bf16x8_t*)&As[wm + mi * 16 + ln15][kgrp * 8];
      acc[mi][0] = __builtin_amdgcn_mfma_f32_16x16x32_bf16(afrag, bfrag[0], acc[mi][0], 0, 0, 0);
      acc[mi][1] = __builtin_amdgcn_mfma_f32_16x16x32_bf16(afrag, bfrag[1], acc[mi][1], 0, 0, 0);
    }
    __syncthreads();
  }

#pragma unroll
  for (int mi = 0; mi < 4; ++mi) {
#pragma unroll
    for (int ni = 0; ni < 2; ++ni) {
      const int ocol = bn + wn + ni * 16 + ln15;
      const float bv = bias[ocol];
      const int orow0 = bm + wm + mi * 16 + kgrp * 4;
#pragma unroll
      for (int r = 0; r < 4; ++r) {
        float o = acc[mi][ni][r] + bv;
        if (ACT == 1) o = gelu_f(o);
        if (OBF) ((__bf16*)C)[(size_t)(orow0 + r) * N + ocol] = (__bf16)o;
        else     C[(size_t)(orow0 + r) * N + ocol] = o;
      }
    }
  }
}

// ---------------- MFMA flash attention --------------------------------------
// Q,K,V bf16 (rows x D_), head slice h*HD_. O fp32 (BT_, D_).
// block = 4 waves; wave w owns q rows [qt*64 + w*16, +16); KV tiles of 32.
// Swapped QK^T: mfma(A=K_tile, B=Q) -> lane holds S[s=kgrp*4+reg][q=ln15].
template<bool CAUSAL>
__global__ __launch_bounds__(256)
void attn_mfma(const __bf16* __restrict__ Q, const __bf16* __restrict__ K,
               const __bf16* __restrict__ V, float* __restrict__ O, int KVROWS) {
  const int b = blockIdx.x >> 3, h = blockIdx.x & 7;
  const int qt = blockIdx.y;
  const int tid = threadIdx.x, lane = tid & 63, wv = tid >> 6;
  const int ln15 = lane & 15, kgrp = lane >> 4, kgrp8 = kgrp * 8;

  __shared__ __bf16 K_lds[32][40];
  __shared__ __bf16 Vt_lds[32][40];     // [hd][kv]
  __shared__ __bf16 P_lds[4][16][40];   // per-wave [q][kv]

  const int q_glob = qt * 64 + wv * 16 + ln15;
  const bf16x8_t qfrag = *(const bf16x8_t*)(Q + ((size_t)(b * T_ + q_glob)) * D_ + h * HD_ + kgrp8);

  const int s_r = tid >> 3, s_c = (tid & 7) * 4;    // staging: row, hd-chunk
  const __bf16* Kb = K + ((size_t)(b * KVROWS + s_r)) * D_ + h * HD_ + s_c;
  const __bf16* Vb = V + ((size_t)(b * KVROWS + s_r)) * D_ + h * HD_ + s_c;

  f32x4_t o0 = (f32x4_t){0.f,0.f,0.f,0.f}, o1 = (f32x4_t){0.f,0.f,0.f,0.f};
  float m = -3.0e38f, l = 0.f;
  const float SCALE = 0.17677669529663689f;   // 1/sqrt(HD)
  const int slim = CAUSAL ? (qt + 1) * 64 : KVROWS;

  for (int s0 = 0; s0 < slim; s0 += 32) {
    // ---- stage K (copy) and V (transpose) into LDS ----
    *(uint2*)&K_lds[s_r][s_c] = *(const uint2*)(Kb + (size_t)s0 * D_);
    bf16x4_t vv = *(const bf16x4_t*)(Vb + (size_t)s0 * D_);
    Vt_lds[s_c + 0][s_r] = vv[0];
    Vt_lds[s_c + 1][s_r] = vv[1];
    Vt_lds[s_c + 2][s_r] = vv[2];
    Vt_lds[s_c + 3][s_r] = vv[3];
    __syncthreads();

    // ---- S^T = K_tile @ Q^T : two 16-row subtiles ----
    bf16x8_t kf0 = *(const bf16x8_t*)&K_lds[ln15][kgrp8];
    bf16x8_t kf1 = *(const bf16x8_t*)&K_lds[16 + ln15][kgrp8];
    f32x4_t sa0 = (f32x4_t){0.f,0.f,0.f,0.f}, sa1 = (f32x4_t){0.f,0.f,0.f,0.f};
    sa0 = __builtin_amdgcn_mfma_f32_16x16x32_bf16(kf0, qfrag, sa0, 0, 0, 0);
    sa1 = __builtin_amdgcn_mfma_f32_16x16x32_bf16(kf1, qfrag, sa1, 0, 0, 0);

    float v[8];
#pragma unroll
    for (int r = 0; r < 4; ++r) { v[r] = sa0[r] * SCALE; v[4 + r] = sa1[r] * SCALE; }
    if (CAUSAL) {
      const int sb = s0 + kgrp * 4;
#pragma unroll
      for (int r = 0; r < 4; ++r) {
        if (sb + r      > q_glob) v[r]     += -1e9f;
        if (sb + 16 + r > q_glob) v[4 + r] += -1e9f;
      }
    }
    float tmax = v[0];
#pragma unroll
    for (int r = 1; r < 8; ++r) tmax = fmaxf(tmax, v[r]);
    tmax = fmaxf(tmax, __shfl_xor(tmax, 16));
    tmax = fmaxf(tmax, __shfl_xor(tmax, 32));
    float mnew = fmaxf(m, tmax);
    float corr = __expf(m - mnew);

    float lsum = 0.f;
    bf16x4_t p0, p1;
#pragma unroll
    for (int r = 0; r < 4; ++r) {
      float e0 = __expf(v[r] - mnew);
      float e1 = __expf(v[4 + r] - mnew);
      lsum += e0 + e1;
      p0[r] = (__bf16)e0;
      p1[r] = (__bf16)e1;
    }
    *(bf16x4_t*)&P_lds[wv][ln15][kgrp * 4]      = p0;
    *(bf16x4_t*)&P_lds[wv][ln15][16 + kgrp * 4] = p1;
    lsum += __shfl_xor(lsum, 16);
    lsum += __shfl_xor(lsum, 32);
    l = l * corr + lsum;
    m = mnew;

    // ---- rescale O (q = kgrp*4 + reg) ----
    const float c0 = __shfl(corr, kgrp * 4 + 0);
    const float c1 = __shfl(corr, kgrp * 4 + 1);
    const float c2 = __shfl(corr, kgrp * 4 + 2);
    const float c3 = __shfl(corr, kgrp * 4 + 3);
    o0[0] *= c0; o0[1] *= c1; o0[2] *= c2; o0[3] *= c3;
    o1[0] *= c0; o1[1] *= c1; o1[2] *= c2; o1[3] *= c3;

    // ---- PV: O[q][hd] += P(16x32) @ V(32x32) ----
    bf16x8_t pf  = *(const bf16x8_t*)&P_lds[wv][ln15][kgrp8];
    bf16x8_t vf0 = *(const bf16x8_t*)&Vt_lds[ln15][kgrp8];
    bf16x8_t vf1 = *(const bf16x8_t*)&Vt_lds[16 + ln15][kgrp8];
    o0 = __builtin_amdgcn_mfma_f32_16x16x32_bf16(pf, vf0, o0, 0, 0, 0);
    o1 = __builtin_amdgcn_mfma_f32_16x16x32_bf16(pf, vf1, o1, 0, 0, 0);
    __syncthreads();
  }

  const float inv = 1.f / l;
  const float i0 = __shfl(inv, kgrp * 4 + 0);
  const float i1 = __shfl(inv, kgrp * 4 + 1);
  const float i2 = __shfl(inv, kgrp * 4 + 2);
  const float i3 = __shfl(inv, kgrp * 4 + 3);
  float* Op = O + ((size_t)(b * T_ + qt * 64 + wv * 16 + kgrp * 4)) * D_ + h * HD_;
  Op[0 * D_ + ln15] = o0[0] * i0;  Op[0 * D_ + 16 + ln15] = o1[0] * i0;
  Op[1 * D_ + ln15] = o0[1] * i1;  Op[1 * D_ + 16 + ln15] = o1[1] * i1;
  Op[2 * D_ + ln15] = o0[2] * i2;  Op[2 * D_ + 16 + ln15] = o1[2] * i2;
  Op[3 * D_ + ln15] = o0[3] * i3;  Op[3 * D_ + 16 + ln15] = o1[3] * i3;
}

// ---------------- fused residual add + LayerNorm (in-place on x) -------------
__global__ __launch_bounds__(256)
void add_ln_kernel(float* __restrict__ x, const float* __restrict__ y,
                   const float* __restrict__ g, const float* __restrict__ bta) {
  const int row = blockIdx.x * 4 + (threadIdx.x >> 6);
  const int lane = threadIdx.x & 63;
  const size_t base = (size_t)row * D_ + lane * 4;
  float4 xv = *(const float4*)&x[base];
  float4 yv = *(const float4*)&y[base];
  float v0 = xv.x + yv.x, v1 = xv.y + yv.y, v2 = xv.z + yv.z, v3 = xv.w + yv.w;
  float sum = v0 + v1 + v2 + v3;
  float sq  = v0 * v0 + v1 * v1 + v2 * v2 + v3 * v3;
#pragma unroll
  for (int off = 32; off; off >>= 1) {
    sum += __shfl_xor(sum, off);
    sq  += __shfl_xor(sq, off);
  }
  float mean = sum * (1.f / D_);
  float var  = sq * (1.f / D_) - mean * mean;
  float rstd = rsqrtf(fmaxf(var, 0.f) + 1e-5f);
  const int c = lane * 4;
  float4 gv = *(const float4*)&g[c];
  float4 bv = *(const float4*)&bta[c];
  float4 ov;
  ov.x = (v0 - mean) * rstd * gv.x + bv.x;
  ov.y = (v1 - mean) * rstd * gv.y + bv.y;
  ov.z = (v2 - mean) * rstd * gv.z + bv.z;
  ov.w = (v3 - mean) * rstd * gv.w + bv.w;
  *(float4*)&x[base] = ov;
}

// ---------------- final matvec: out = h(BTx128) @ Wp2(128x1) + bp2 -----------
__global__ __launch_bounds__(256)
void head2_kernel(const float* __restrict__ hb, const float* __restrict__ w,
                  const float* __restrict__ bias, float* __restrict__ out) {
  const int row = blockIdx.x * 4 + (threadIdx.x >> 6);
  const int lane = threadIdx.x & 63;
  float a = hb[(size_t)row * 128 + lane] * w[lane]
          + hb[(size_t)row * 128 + 64 + lane] * w[64 + lane];
#pragma unroll
  for (int off = 32; off; off >>= 1) a += __shfl_xor(a, off);
  if (lane == 0) out[row] = a + bias[0];
}

extern "C" void kernel_launch(void* const* d_in, const int* in_sizes, int n_in,
                              void* d_out, int out_size, void* d_ws, size_t ws_size,
                              hipStream_t stream) {
  const float* tgt    = (const float*)d_in[0];
  const float* memory = (const float*)d_in[1];
  const float* W_emb  = (const float*)d_in[2];
  const float* b_emb  = (const float*)d_in[3];
  const float* W_enc  = (const float*)d_in[4];
  const float* b_enc  = (const float*)d_in[5];
  const float* Wq_s = (const float*)d_in[6];  const float* bq_s = (const float*)d_in[7];
  const float* Wk_s = (const float*)d_in[8];  const float* bk_s = (const float*)d_in[9];
  const float* Wv_s = (const float*)d_in[10]; const float* bv_s = (const float*)d_in[11];
  const float* Wo_s = (const float*)d_in[12]; const float* bo_s = (const float*)d_in[13];
  const float* Wq_c = (const float*)d_in[14]; const float* bq_c = (const float*)d_in[15];
  const float* Wk_c = (const float*)d_in[16]; const float* bk_c = (const float*)d_in[17];
  const float* Wv_c = (const float*)d_in[18]; const float* bv_c = (const float*)d_in[19];
  const float* Wo_c = (const float*)d_in[20]; const float* bo_c = (const float*)d_in[21];
  const float* g1  = (const float*)d_in[22]; const float* be1 = (const float*)d_in[23];
  const float* g2  = (const float*)d_in[24]; const float* be2 = (const float*)d_in[25];
  const float* g3  = (const float*)d_in[26]; const float* be3 = (const float*)d_in[27];
  const float* Wf1 = (const float*)d_in[28]; const float* bf1 = (const float*)d_in[29];
  const float* Wf2 = (const float*)d_in[30]; const float* bf2 = (const float*)d_in[31];
  const float* Wp1 = (const float*)d_in[32]; const float* bp1 = (const float*)d_in[33];
  const float* Wp2 = (const float*)d_in[34]; const float* bp2 = (const float*)d_in[35];

  // workspace (float units): x | mem | y | scr | wt(bf16)
  float* x   = (float*)d_ws;                   // 4,194,304 f
  float* mem = x + (size_t)BT_ * D_;           // 2,097,152 f
  float* y   = mem + (size_t)BS_ * D_;         // 4,194,304 f
  float* scr = y + (size_t)BT_ * D_;           // 16,777,216 f
  // q,k,v bf16 inside scr; ao fp32 after them; ff aliases whole scr
  __bf16* q = (__bf16*)scr;                            // BT*D bf16 = 2,097,152 f
  __bf16* k = (__bf16*)(scr + (size_t)BT_ * D_ / 2);   // next 2,097,152 f
  __bf16* v = (__bf16*)(scr + (size_t)BT_ * D_);       // next
  float*  ao = scr + (size_t)BT_ * D_ * 3 / 2;         // 4,194,304 f
  float*  ff = scr;
  __bf16* wt = (__bf16*)(scr + (size_t)BT_ * FF_);

  const size_t o_enc = 0;
  const size_t o_qs = 196608,  o_ks = 458752,  o_vs = 720896,  o_os = 983040;
  const size_t o_qc = 1245184, o_kc = 1507328, o_vc = 1769472, o_oc = 2031616;
  const size_t o_f1 = 2293760, o_f2 = 3342336, o_p1 = 4390912;
  const size_t WSTR = 65536;
  const size_t FSTR = 262144;

  TDs td;
  td.d[0]  = {W_enc, o_enc, ED_, D_, 1};
  td.d[1]  = {Wq_s, o_qs, D_, D_, L_};
  td.d[2]  = {Wk_s, o_ks, D_, D_, L_};
  td.d[3]  = {Wv_s, o_vs, D_, D_, L_};
  td.d[4]  = {Wo_s, o_os, D_, D_, L_};
  td.d[5]  = {Wq_c, o_qc, D_, D_, L_};
  td.d[6]  = {Wk_c, o_kc, D_, D_, L_};
  td.d[7]  = {Wv_c, o_vc, D_, D_, L_};
  td.d[8]  = {Wo_c, o_oc, D_, D_, L_};
  td.d[9]  = {Wf1, o_f1, D_, FF_, L_};
  td.d[10] = {Wf2, o_f2, FF_, D_, L_};
  td.d[11] = {Wp1, o_p1, D_, 128, 1};

  dim3 blk(256);
  transpose_cvt_kernel<<<dim3(1024, 12), blk, 0, stream>>>(td, wt);

  const dim3 gP(D_ / 64, BT_ / 128);
  const dim3 gM(D_ / 64, BS_ / 128);
  const dim3 gA(B_ * H_, T_ / 64);

  embed_kernel<<<BT_ * D_ / 256, blk, 0, stream>>>(tgt, W_emb, b_emb, x);
  gemm_mfma<0,0><<<gM, blk, 0, stream>>>(memory, wt + o_enc, b_enc, mem, BS_, D_, ED_);

  for (int i = 0; i < L_; ++i) {
    // ---- self attention ----
    gemm_mfma<0,1><<<gP, blk, 0, stream>>>(x, wt + o_qs + i * WSTR, bq_s + i * D_, (float*)q, BT_, D_, D_);
    gemm_mfma<0,1><<<gP, blk, 0, stream>>>(x, wt + o_ks + i * WSTR, bk_s + i * D_, (float*)k, BT_, D_, D_);
    gemm_mfma<0,1><<<gP, blk, 0, stream>>>(x, wt + o_vs + i * WSTR, bv_s + i * D_, (float*)v, BT_, D_, D_);
    attn_mfma<true><<<gA, blk, 0, stream>>>(q, k, v, ao, T_);
    gemm_mfma<0,0><<<gP, blk, 0, stream>>>(ao, wt + o_os + i * WSTR, bo_s + i * D_, y, BT_, D_, D_);
    add_ln_kernel<<<BT_ / 4, blk, 0, stream>>>(x, y, g1 + i * D_, be1 + i * D_);
    // ---- cross attention ----
    gemm_mfma<0,1><<<gP, blk, 0, stream>>>(x, wt + o_qc + i * WSTR, bq_c + i * D_, (float*)q, BT_, D_, D_);
    gemm_mfma<0,1><<<gM, blk, 0, stream>>>(mem, wt + o_kc + i * WSTR, bk_c + i * D_, (float*)k, BS_, D_, D_);
    gemm_mfma<0,1><<<gM, blk, 0, stream>>>(mem, wt + o_vc + i * WSTR, bv_c + i * D_, (float*)v, BS_, D_, D_);
    attn_mfma<false><<<gA, blk, 0, stream>>>(q, k, v, ao, S_);
    gemm_mfma<0,0><<<gP, blk, 0, stream>>>(ao, wt + o_oc + i * WSTR, bo_c + i * D_, y, BT_, D_, D_);
    add_ln_kernel<<<BT_ / 4, blk, 0, stream>>>(x, y, g2 + i * D_, be2 + i * D_);
    // ---- feed-forward ----
    gemm_mfma<1,0><<<dim3(FF_ / 64, BT_ / 128), blk, 0, stream>>>(x, wt + o_f1 + i * FSTR, bf1 + i * FF_, ff, BT_, FF_, D_);
    gemm_mfma<0,0><<<dim3(D_ / 64, BT_ / 128), blk, 0, stream>>>(ff, wt + o_f2 + i * FSTR, bf2 + i * D_, y, BT_, D_, FF_);
    add_ln_kernel<<<BT_ / 4, blk, 0, stream>>>(x, y, g3 + i * D_, be3 + i * D_);
  }
  // ---- head ----
  gemm_mfma<1,0><<<dim3(2, BT_ / 128), blk, 0, stream>>>(x, wt + o_p1, bp1, y, BT_, 128, D_);
  head2_kernel<<<BT_ / 4, blk, 0, stream>>>(y, Wp2, bp2, (float*)d_out);
}

// Round 4
// 831.061 us; speedup vs baseline: 3.7403x; 1.3360x over previous
//
#include <hip/hip_runtime.h>
#include <math.h>

#define B_  32
#define T_  512
#define S_  256
#define D_  256
#define H_  8
#define HD_ 32
#define FF_ 1024
#define ED_ 768
#define L_  4
#define BT_ (B_*T_)   // 16384
#define BS_ (B_*S_)   // 8192

typedef __bf16 bf16x8_t __attribute__((ext_vector_type(8)));
typedef __bf16 bf16x4_t __attribute__((ext_vector_type(4)));
typedef float  f32x4_t  __attribute__((ext_vector_type(4)));

__device__ __forceinline__ float gelu_f(float v) {
  return 0.5f * v * (1.f + erff(v * 0.7071067811865476f));
}

// ---------------- embed: x = tgt*W_emb + b_emb + pos_encoding ----------------
__global__ __launch_bounds__(256)
void embed_kernel(const float* __restrict__ tgt, const float* __restrict__ Wemb,
                  const float* __restrict__ bemb, float* __restrict__ x,
                  __bf16* __restrict__ xbf) {
  int i = blockIdx.x * 256 + threadIdx.x;
  int d  = i & (D_ - 1);
  int bt = i >> 8;
  int t  = bt & (T_ - 1);
  int p  = d >> 1;
  float div = expf((float)(2 * p) * (-9.210340371976184f / (float)D_));
  float arg = (float)t * div;
  float pe = (d & 1) ? cosf(arg) : sinf(arg);
  float v = tgt[bt] * Wemb[d] + bemb[d] + pe;
  x[i] = v;
  xbf[i] = (__bf16)v;
}

// ---------------- fp32 -> bf16 bulk convert ----------------------------------
__global__ __launch_bounds__(256)
void cvt_bf16_kernel(const float* __restrict__ in, __bf16* __restrict__ out) {
  int i = (blockIdx.x * 256 + threadIdx.x) * 4;
  float4 v = *(const float4*)(in + i);
  bf16x4_t o;
  o[0] = (__bf16)v.x; o[1] = (__bf16)v.y; o[2] = (__bf16)v.z; o[3] = (__bf16)v.w;
  *(bf16x4_t*)(out + i) = o;
}

// ------------- weight pre-pass: transpose [K][N] fp32 -> [N][K] bf16 ---------
struct TD { const float* src; size_t dst; int K, N, nb; };
struct TDs { TD d[12]; };

__global__ __launch_bounds__(256)
void transpose_cvt_kernel(TDs a, __bf16* __restrict__ wt) {
  __shared__ float tile[32][33];
  TD t = a.d[blockIdx.y];
  const int kt = t.K >> 5, nt = t.N >> 5;
  const int per = kt * nt, tot = per * t.nb;
  const int id = blockIdx.x;
  if (id >= tot) return;
  const int b = id / per;
  const int r2 = id - b * per;
  const int kti = r2 / nt;
  const int nti = r2 - kti * nt;
  const int c = threadIdx.x & 31, r0 = threadIdx.x >> 5;
  const float* src = t.src + (size_t)b * t.K * t.N;
  __bf16* dst = wt + t.dst + (size_t)b * t.K * t.N;
#pragma unroll
  for (int j = 0; j < 4; ++j) {
    int rr = r0 + j * 8;
    tile[rr][c] = src[(size_t)(kti * 32 + rr) * t.N + nti * 32 + c];
  }
  __syncthreads();
#pragma unroll
  for (int j = 0; j < 4; ++j) {
    int rr = r0 + j * 8;
    dst[(size_t)(nti * 32 + rr) * t.K + kti * 32 + c] = (__bf16)tile[c][rr];
  }
}

// ---------------- bf16 MFMA GEMM: C = A(MxK,bf16) @ Wt(NxK,bf16)^T + bias ----
// 1-D grid, XCD-chunked swizzle: all nN blocks of one 128-row A-panel land on
// the same XCD (consecutive per-XCD slots) -> panel read once per XCD L2.
// block 256 thr = 4 waves (2x2), tile 128x64, BK=32, per-wave 4x2 16x16 frags.
template<int ACT, int OBF>
__global__ __launch_bounds__(256, 4)
void gemm_bf(const __bf16* __restrict__ A, const __bf16* __restrict__ Bt,
             const float* __restrict__ bias, void* __restrict__ Cv,
             int N, int K, int nNlog, int ppx) {
  __shared__ __bf16 As[128][40];
  __shared__ __bf16 Bs[64][40];
  const int tid  = threadIdx.x;
  const int lane = tid & 63;
  const int wv   = tid >> 6;
  const int wm = (wv & 1) * 64;
  const int wn = (wv >> 1) * 32;
  const int ln15 = lane & 15;
  const int kgrp = lane >> 4, kgrp8 = kgrp * 8;
  const int xcd = blockIdx.x & 7, j = blockIdx.x >> 3;
  const int bm = (xcd * ppx + (j >> nNlog)) * 128;
  const int bn = (j & ((1 << nNlog) - 1)) * 64;

  const int s_row = tid >> 2, s_kc = (tid & 3) * 8;
  const __bf16* a_base = A + (size_t)(bm + s_row) * K + s_kc;
  const __bf16* b_base = Bt + (size_t)(bn + s_row) * K + s_kc;

  f32x4_t acc[4][2];
#pragma unroll
  for (int mi = 0; mi < 4; ++mi)
#pragma unroll
    for (int ni = 0; ni < 2; ++ni) acc[mi][ni] = (f32x4_t){0.f, 0.f, 0.f, 0.f};

  for (int k0 = 0; k0 < K; k0 += 32) {
    *(bf16x8_t*)&As[s_row][s_kc]      = *(const bf16x8_t*)(a_base + k0);
    *(bf16x8_t*)&As[64 + s_row][s_kc] = *(const bf16x8_t*)(a_base + (size_t)64 * K + k0);
    *(bf16x8_t*)&Bs[s_row][s_kc]      = *(const bf16x8_t*)(b_base + k0);
    __syncthreads();

    bf16x8_t bfrag[2];
#pragma unroll
    for (int ni = 0; ni < 2; ++ni)
      bfrag[ni] = *(const bf16x8_t*)&Bs[wn + ni * 16 + ln15][kgrp8];
#pragma unroll
    for (int mi = 0; mi < 4; ++mi) {
      bf16x8_t afrag = *(const bf16x8_t*)&As[wm + mi * 16 + ln15][kgrp8];
      acc[mi][0] = __builtin_amdgcn_mfma_f32_16x16x32_bf16(afrag, bfrag[0], acc[mi][0], 0, 0, 0);
      acc[mi][1] = __builtin_amdgcn_mfma_f32_16x16x32_bf16(afrag, bfrag[1], acc[mi][1], 0, 0, 0);
    }
    __syncthreads();
  }

#pragma unroll
  for (int mi = 0; mi < 4; ++mi) {
#pragma unroll
    for (int ni = 0; ni < 2; ++ni) {
      const int ocol = bn + wn + ni * 16 + ln15;
      const float bv = bias[ocol];
      const int orow0 = bm + wm + mi * 16 + kgrp * 4;
#pragma unroll
      for (int r = 0; r < 4; ++r) {
        float o = acc[mi][ni][r] + bv;
        if (ACT == 1) o = gelu_f(o);
        if (OBF) ((__bf16*)Cv)[(size_t)(orow0 + r) * N + ocol] = (__bf16)o;
        else     ((float*)Cv)[(size_t)(orow0 + r) * N + ocol] = o;
      }
    }
  }
}

// ---------------- MFMA flash attention (bf16 in, bf16 out) -------------------
// block = 4 waves; wave w owns q rows [qt*64 + w*16, +16); KV tiles of 32.
// Swapped QK^T: mfma(A=K_tile, B=Q) -> lane holds S[s=kgrp*4+reg][q=ln15].
template<bool CAUSAL>
__global__ __launch_bounds__(256)
void attn_mfma(const __bf16* __restrict__ Q, const __bf16* __restrict__ K,
               const __bf16* __restrict__ V, __bf16* __restrict__ O, int KVROWS) {
  const int b = blockIdx.x >> 3, h = blockIdx.x & 7;
  const int qt = blockIdx.y;
  const int tid = threadIdx.x, lane = tid & 63, wv = tid >> 6;
  const int ln15 = lane & 15, kgrp = lane >> 4, kgrp8 = kgrp * 8;

  __shared__ __bf16 K_lds[32][40];
  __shared__ __bf16 Vt_lds[32][40];     // [hd][kv]
  __shared__ __bf16 P_lds[4][16][40];   // per-wave [q][kv]

  const int q_glob = qt * 64 + wv * 16 + ln15;
  const bf16x8_t qfrag = *(const bf16x8_t*)(Q + ((size_t)(b * T_ + q_glob)) * D_ + h * HD_ + kgrp8);

  const int s_r = tid >> 3, s_c = (tid & 7) * 4;
  const __bf16* Kb = K + ((size_t)(b * KVROWS + s_r)) * D_ + h * HD_ + s_c;
  const __bf16* Vb = V + ((size_t)(b * KVROWS + s_r)) * D_ + h * HD_ + s_c;

  f32x4_t o0 = (f32x4_t){0.f,0.f,0.f,0.f}, o1 = (f32x4_t){0.f,0.f,0.f,0.f};
  float m = -3.0e38f, l = 0.f;
  const float SCALE = 0.17677669529663689f;
  const int slim = CAUSAL ? (qt + 1) * 64 : KVROWS;

  for (int s0 = 0; s0 < slim; s0 += 32) {
    *(uint2*)&K_lds[s_r][s_c] = *(const uint2*)(Kb + (size_t)s0 * D_);
    bf16x4_t vv = *(const bf16x4_t*)(Vb + (size_t)s0 * D_);
    Vt_lds[s_c + 0][s_r] = vv[0];
    Vt_lds[s_c + 1][s_r] = vv[1];
    Vt_lds[s_c + 2][s_r] = vv[2];
    Vt_lds[s_c + 3][s_r] = vv[3];
    __syncthreads();

    bf16x8_t kf0 = *(const bf16x8_t*)&K_lds[ln15][kgrp8];
    bf16x8_t kf1 = *(const bf16x8_t*)&K_lds[16 + ln15][kgrp8];
    f32x4_t sa0 = (f32x4_t){0.f,0.f,0.f,0.f}, sa1 = (f32x4_t){0.f,0.f,0.f,0.f};
    sa0 = __builtin_amdgcn_mfma_f32_16x16x32_bf16(kf0, qfrag, sa0, 0, 0, 0);
    sa1 = __builtin_amdgcn_mfma_f32_16x16x32_bf16(kf1, qfrag, sa1, 0, 0, 0);

    float v[8];
#pragma unroll
    for (int r = 0; r < 4; ++r) { v[r] = sa0[r] * SCALE; v[4 + r] = sa1[r] * SCALE; }
    if (CAUSAL) {
      const int sb = s0 + kgrp * 4;
#pragma unroll
      for (int r = 0; r < 4; ++r) {
        if (sb + r      > q_glob) v[r]     += -1e9f;
        if (sb + 16 + r > q_glob) v[4 + r] += -1e9f;
      }
    }
    float tmax = v[0];
#pragma unroll
    for (int r = 1; r < 8; ++r) tmax = fmaxf(tmax, v[r]);
    tmax = fmaxf(tmax, __shfl_xor(tmax, 16));
    tmax = fmaxf(tmax, __shfl_xor(tmax, 32));
    float mnew = fmaxf(m, tmax);
    float corr = __expf(m - mnew);

    float lsum = 0.f;
    bf16x4_t p0, p1;
#pragma unroll
    for (int r = 0; r < 4; ++r) {
      float e0 = __expf(v[r] - mnew);
      float e1 = __expf(v[4 + r] - mnew);
      lsum += e0 + e1;
      p0[r] = (__bf16)e0;
      p1[r] = (__bf16)e1;
    }
    *(bf16x4_t*)&P_lds[wv][ln15][kgrp * 4]      = p0;
    *(bf16x4_t*)&P_lds[wv][ln15][16 + kgrp * 4] = p1;
    lsum += __shfl_xor(lsum, 16);
    lsum += __shfl_xor(lsum, 32);
    l = l * corr + lsum;
    m = mnew;

    const float c0 = __shfl(corr, kgrp * 4 + 0);
    const float c1 = __shfl(corr, kgrp * 4 + 1);
    const float c2 = __shfl(corr, kgrp * 4 + 2);
    const float c3 = __shfl(corr, kgrp * 4 + 3);
    o0[0] *= c0; o0[1] *= c1; o0[2] *= c2; o0[3] *= c3;
    o1[0] *= c0; o1[1] *= c1; o1[2] *= c2; o1[3] *= c3;

    bf16x8_t pf  = *(const bf16x8_t*)&P_lds[wv][ln15][kgrp8];
    bf16x8_t vf0 = *(const bf16x8_t*)&Vt_lds[ln15][kgrp8];
    bf16x8_t vf1 = *(const bf16x8_t*)&Vt_lds[16 + ln15][kgrp8];
    o0 = __builtin_amdgcn_mfma_f32_16x16x32_bf16(pf, vf0, o0, 0, 0, 0);
    o1 = __builtin_amdgcn_mfma_f32_16x16x32_bf16(pf, vf1, o1, 0, 0, 0);
    __syncthreads();
  }

  const float inv = 1.f / l;
  const float i0 = __shfl(inv, kgrp * 4 + 0);
  const float i1 = __shfl(inv, kgrp * 4 + 1);
  const float i2 = __shfl(inv, kgrp * 4 + 2);
  const float i3 = __shfl(inv, kgrp * 4 + 3);
  __bf16* Op = O + ((size_t)(b * T_ + qt * 64 + wv * 16 + kgrp * 4)) * D_ + h * HD_;
  Op[0 * D_ + ln15] = (__bf16)(o0[0] * i0);  Op[0 * D_ + 16 + ln15] = (__bf16)(o1[0] * i0);
  Op[1 * D_ + ln15] = (__bf16)(o0[1] * i1);  Op[1 * D_ + 16 + ln15] = (__bf16)(o1[1] * i1);
  Op[2 * D_ + ln15] = (__bf16)(o0[2] * i2);  Op[2 * D_ + 16 + ln15] = (__bf16)(o1[2] * i2);
  Op[3 * D_ + ln15] = (__bf16)(o0[3] * i3);  Op[3 * D_ + 16 + ln15] = (__bf16)(o1[3] * i3);
}

// ------ fused residual add + LayerNorm (fp32 x in-place, + bf16 copy) --------
__global__ __launch_bounds__(256)
void add_ln_kernel(float* __restrict__ x, __bf16* __restrict__ xbf,
                   const float* __restrict__ y,
                   const float* __restrict__ g, const float* __restrict__ bta) {
  const int row = blockIdx.x * 4 + (threadIdx.x >> 6);
  const int lane = threadIdx.x & 63;
  const size_t base = (size_t)row * D_ + lane * 4;
  float4 xv = *(const float4*)&x[base];
  float4 yv = *(const float4*)&y[base];
  float v0 = xv.x + yv.x, v1 = xv.y + yv.y, v2 = xv.z + yv.z, v3 = xv.w + yv.w;
  float sum = v0 + v1 + v2 + v3;
  float sq  = v0 * v0 + v1 * v1 + v2 * v2 + v3 * v3;
#pragma unroll
  for (int off = 32; off; off >>= 1) {
    sum += __shfl_xor(sum, off);
    sq  += __shfl_xor(sq, off);
  }
  float mean = sum * (1.f / D_);
  float var  = sq * (1.f / D_) - mean * mean;
  float rstd = rsqrtf(fmaxf(var, 0.f) + 1e-5f);
  const int c = lane * 4;
  float4 gv = *(const float4*)&g[c];
  float4 bv = *(const float4*)&bta[c];
  float4 ov;
  ov.x = (v0 - mean) * rstd * gv.x + bv.x;
  ov.y = (v1 - mean) * rstd * gv.y + bv.y;
  ov.z = (v2 - mean) * rstd * gv.z + bv.z;
  ov.w = (v3 - mean) * rstd * gv.w + bv.w;
  *(float4*)&x[base] = ov;
  bf16x4_t ob;
  ob[0] = (__bf16)ov.x; ob[1] = (__bf16)ov.y; ob[2] = (__bf16)ov.z; ob[3] = (__bf16)ov.w;
  *(bf16x4_t*)&xbf[base] = ob;
}

// ---------------- final matvec: out = h(BTx128) @ Wp2(128x1) + bp2 -----------
__global__ __launch_bounds__(256)
void head2_kernel(const float* __restrict__ hb, const float* __restrict__ w,
                  const float* __restrict__ bias, float* __restrict__ out) {
  const int row = blockIdx.x * 4 + (threadIdx.x >> 6);
  const int lane = threadIdx.x & 63;
  float a = hb[(size_t)row * 128 + lane] * w[lane]
          + hb[(size_t)row * 128 + 64 + lane] * w[64 + lane];
#pragma unroll
  for (int off = 32; off; off >>= 1) a += __shfl_xor(a, off);
  if (lane == 0) out[row] = a + bias[0];
}

extern "C" void kernel_launch(void* const* d_in, const int* in_sizes, int n_in,
                              void* d_out, int out_size, void* d_ws, size_t ws_size,
                              hipStream_t stream) {
  const float* tgt    = (const float*)d_in[0];
  const float* memory = (const float*)d_in[1];
  const float* W_emb  = (const float*)d_in[2];
  const float* b_emb  = (const float*)d_in[3];
  const float* W_enc  = (const float*)d_in[4];
  const float* b_enc  = (const float*)d_in[5];
  const float* Wq_s = (const float*)d_in[6];  const float* bq_s = (const float*)d_in[7];
  const float* Wk_s = (const float*)d_in[8];  const float* bk_s = (const float*)d_in[9];
  const float* Wv_s = (const float*)d_in[10]; const float* bv_s = (const float*)d_in[11];
  const float* Wo_s = (const float*)d_in[12]; const float* bo_s = (const float*)d_in[13];
  const float* Wq_c = (const float*)d_in[14]; const float* bq_c = (const float*)d_in[15];
  const float* Wk_c = (const float*)d_in[16]; const float* bk_c = (const float*)d_in[17];
  const float* Wv_c = (const float*)d_in[18]; const float* bv_c = (const float*)d_in[19];
  const float* Wo_c = (const float*)d_in[20]; const float* bo_c = (const float*)d_in[21];
  const float* g1  = (const float*)d_in[22]; const float* be1 = (const float*)d_in[23];
  const float* g2  = (const float*)d_in[24]; const float* be2 = (const float*)d_in[25];
  const float* g3  = (const float*)d_in[26]; const float* be3 = (const float*)d_in[27];
  const float* Wf1 = (const float*)d_in[28]; const float* bf1 = (const float*)d_in[29];
  const float* Wf2 = (const float*)d_in[30]; const float* bf2 = (const float*)d_in[31];
  const float* Wp1 = (const float*)d_in[32]; const float* bp1 = (const float*)d_in[33];
  const float* Wp2 = (const float*)d_in[34]; const float* bp2 = (const float*)d_in[35];

  // workspace (float units):
  float*  x    = (float*)d_ws;                          // BT*D f32      4,194,304
  float*  y    = x + (size_t)BT_ * D_;                  // BT*D f32      4,194,304
  __bf16* xbf  = (__bf16*)(y + (size_t)BT_ * D_);       // BT*D bf16     2,097,152 f
  __bf16* membf= xbf + (size_t)BT_ * D_;                // BS*D bf16     1,048,576 f
  __bf16* memb = membf + (size_t)BS_ * D_;              // BS*ED bf16    3,145,728 f
  __bf16* q    = memb + (size_t)BS_ * ED_;              // BT*D bf16
  __bf16* k    = q + (size_t)BT_ * D_;
  __bf16* v    = k + (size_t)BT_ * D_;
  __bf16* ao   = v + (size_t)BT_ * D_;
  __bf16* ff   = q;                                     // aliases q..ao = BT*FF bf16
  __bf16* wt   = ao + (size_t)BT_ * D_;                 // 4,456,448 bf16

  const size_t o_enc = 0;
  const size_t o_qs = 196608,  o_ks = 458752,  o_vs = 720896,  o_os = 983040;
  const size_t o_qc = 1245184, o_kc = 1507328, o_vc = 1769472, o_oc = 2031616;
  const size_t o_f1 = 2293760, o_f2 = 3342336, o_p1 = 4390912;
  const size_t WSTR = 65536;
  const size_t FSTR = 262144;

  TDs td;
  td.d[0]  = {W_enc, o_enc, ED_, D_, 1};
  td.d[1]  = {Wq_s, o_qs, D_, D_, L_};
  td.d[2]  = {Wk_s, o_ks, D_, D_, L_};
  td.d[3]  = {Wv_s, o_vs, D_, D_, L_};
  td.d[4]  = {Wo_s, o_os, D_, D_, L_};
  td.d[5]  = {Wq_c, o_qc, D_, D_, L_};
  td.d[6]  = {Wk_c, o_kc, D_, D_, L_};
  td.d[7]  = {Wv_c, o_vc, D_, D_, L_};
  td.d[8]  = {Wo_c, o_oc, D_, D_, L_};
  td.d[9]  = {Wf1, o_f1, D_, FF_, L_};
  td.d[10] = {Wf2, o_f2, FF_, D_, L_};
  td.d[11] = {Wp1, o_p1, D_, 128, 1};

  dim3 blk(256);
  transpose_cvt_kernel<<<dim3(1024, 12), blk, 0, stream>>>(td, wt);
  cvt_bf16_kernel<<<BS_ * ED_ / 1024, blk, 0, stream>>>(memory, memb);
  embed_kernel<<<BT_ * D_ / 256, blk, 0, stream>>>(tgt, W_emb, b_emb, x, xbf);

  // grids: W = nN * nM blocks (1-D, swizzled inside kernel)
  const int gP = 4 * 128;    // BT rows, N=256
  const int gM = 4 * 64;     // BS rows, N=256
  const dim3 gA(B_ * H_, T_ / 64);

  gemm_bf<0,1><<<gM, blk, 0, stream>>>(memb, wt + o_enc, b_enc, membf, D_, ED_, 2, 8);

  for (int i = 0; i < L_; ++i) {
    // ---- self attention ----
    gemm_bf<0,1><<<gP, blk, 0, stream>>>(xbf, wt + o_qs + i * WSTR, bq_s + i * D_, q, D_, D_, 2, 16);
    gemm_bf<0,1><<<gP, blk, 0, stream>>>(xbf, wt + o_ks + i * WSTR, bk_s + i * D_, k, D_, D_, 2, 16);
    gemm_bf<0,1><<<gP, blk, 0, stream>>>(xbf, wt + o_vs + i * WSTR, bv_s + i * D_, v, D_, D_, 2, 16);
    attn_mfma<true><<<gA, blk, 0, stream>>>(q, k, v, ao, T_);
    gemm_bf<0,0><<<gP, blk, 0, stream>>>(ao, wt + o_os + i * WSTR, bo_s + i * D_, y, D_, D_, 2, 16);
    add_ln_kernel<<<BT_ / 4, blk, 0, stream>>>(x, xbf, y, g1 + i * D_, be1 + i * D_);
    // ---- cross attention ----
    gemm_bf<0,1><<<gP, blk, 0, stream>>>(xbf, wt + o_qc + i * WSTR, bq_c + i * D_, q, D_, D_, 2, 16);
    gemm_bf<0,1><<<gM, blk, 0, stream>>>(membf, wt + o_kc + i * WSTR, bk_c + i * D_, k, D_, D_, 2, 8);
    gemm_bf<0,1><<<gM, blk, 0, stream>>>(membf, wt + o_vc + i * WSTR, bv_c + i * D_, v, D_, D_, 2, 8);
    attn_mfma<false><<<gA, blk, 0, stream>>>(q, k, v, ao, S_);
    gemm_bf<0,0><<<gP, blk, 0, stream>>>(ao, wt + o_oc + i * WSTR, bo_c + i * D_, y, D_, D_, 2, 16);
    add_ln_kernel<<<BT_ / 4, blk, 0, stream>>>(x, xbf, y, g2 + i * D_, be2 + i * D_);
    // ---- feed-forward ----
    gemm_bf<1,1><<<16 * 128, blk, 0, stream>>>(xbf, wt + o_f1 + i * FSTR, bf1 + i * FF_, ff, FF_, D_, 4, 16);
    gemm_bf<0,0><<<gP, blk, 0, stream>>>(ff, wt + o_f2 + i * FSTR, bf2 + i * D_, y, D_, FF_, 2, 16);
    add_ln_kernel<<<BT_ / 4, blk, 0, stream>>>(x, xbf, y, g3 + i * D_, be3 + i * D_);
  }
  // ---- head ----
  gemm_bf<1,0><<<2 * 128, blk, 0, stream>>>(xbf, wt + o_p1, bp1, y, 128, D_, 1, 16);
  head2_kernel<<<BT_ / 4, blk, 0, stream>>>(y, Wp2, bp2, (float*)d_out);
}

// Round 5
// 752.350 us; speedup vs baseline: 4.1316x; 1.1046x over previous
//
#include <hip/hip_runtime.h>
#include <math.h>

#define B_  32
#define T_  512
#define S_  256
#define D_  256
#define H_  8
#define HD_ 32
#define FF_ 1024
#define ED_ 768
#define L_  4
#define BT_ (B_*T_)   // 16384
#define BS_ (B_*S_)   // 8192

typedef __bf16 bf16x8_t __attribute__((ext_vector_type(8)));
typedef __bf16 bf16x4_t __attribute__((ext_vector_type(4)));
typedef float  f32x4_t  __attribute__((ext_vector_type(4)));

__device__ __forceinline__ float gelu_f(float v) {
  return 0.5f * v * (1.f + erff(v * 0.7071067811865476f));
}

// async global->LDS, 16B per lane; LDS dest = uniform base + lane*16
__device__ __forceinline__ void gl16(const __bf16* gsrc, __bf16* ldst) {
  __builtin_amdgcn_global_load_lds(
      (const __attribute__((address_space(1))) unsigned int*)gsrc,
      (__attribute__((address_space(3))) unsigned int*)ldst, 16, 0, 0);
}

// ---------------- embed: x = tgt*W_emb + b_emb + pos_encoding ----------------
__global__ __launch_bounds__(256)
void embed_kernel(const float* __restrict__ tgt, const float* __restrict__ Wemb,
                  const float* __restrict__ bemb, float* __restrict__ x,
                  __bf16* __restrict__ xbf) {
  int i = blockIdx.x * 256 + threadIdx.x;
  int d  = i & (D_ - 1);
  int bt = i >> 8;
  int t  = bt & (T_ - 1);
  int p  = d >> 1;
  float div = expf((float)(2 * p) * (-9.210340371976184f / (float)D_));
  float arg = (float)t * div;
  float pe = (d & 1) ? cosf(arg) : sinf(arg);
  float v = tgt[bt] * Wemb[d] + bemb[d] + pe;
  x[i] = v;
  xbf[i] = (__bf16)v;
}

// ---------------- fp32 -> bf16 bulk convert ----------------------------------
__global__ __launch_bounds__(256)
void cvt_bf16_kernel(const float* __restrict__ in, __bf16* __restrict__ out) {
  int i = (blockIdx.x * 256 + threadIdx.x) * 4;
  float4 v = *(const float4*)(in + i);
  bf16x4_t o;
  o[0] = (__bf16)v.x; o[1] = (__bf16)v.y; o[2] = (__bf16)v.z; o[3] = (__bf16)v.w;
  *(bf16x4_t*)(out + i) = o;
}

// ------------- weight pre-pass: transpose [K][N] fp32 -> [N][K] bf16 ---------
struct TD { const float* src; size_t dst; int K, N, nb; size_t lstride; };
struct TDs { TD d[12]; };

__global__ __launch_bounds__(256)
void transpose_cvt_kernel(TDs a, __bf16* __restrict__ wt) {
  __shared__ float tile[32][33];
  TD t = a.d[blockIdx.y];
  const int kt = t.K >> 5, nt = t.N >> 5;
  const int per = kt * nt, tot = per * t.nb;
  const int id = blockIdx.x;
  if (id >= tot) return;
  const int b = id / per;
  const int r2 = id - b * per;
  const int kti = r2 / nt;
  const int nti = r2 - kti * nt;
  const int c = threadIdx.x & 31, r0 = threadIdx.x >> 5;
  const float* src = t.src + (size_t)b * t.K * t.N;
  __bf16* dst = wt + t.dst + (size_t)b * t.lstride;
#pragma unroll
  for (int j = 0; j < 4; ++j) {
    int rr = r0 + j * 8;
    tile[rr][c] = src[(size_t)(kti * 32 + rr) * t.N + nti * 32 + c];
  }
  __syncthreads();
#pragma unroll
  for (int j = 0; j < 4; ++j) {
    int rr = r0 + j * 8;
    dst[(size_t)(nti * 32 + rr) * t.K + kti * 32 + c] = (__bf16)tile[c][rr];
  }
}

// ---------------- concat biases: [L][768] self-qkv, then [L][512] cross-kv ---
__global__ __launch_bounds__(256)
void bias_concat_kernel(const float* __restrict__ bq_s, const float* __restrict__ bk_s,
                        const float* __restrict__ bv_s, const float* __restrict__ bk_c,
                        const float* __restrict__ bv_c, float* __restrict__ dst) {
  int idx = blockIdx.x * 256 + threadIdx.x;
  if (idx >= 5120) return;
  if (idx < 3072) {
    int l = idx / 768, c = idx - l * 768;
    float v = (c < 256) ? bq_s[l * 256 + c]
            : (c < 512) ? bk_s[l * 256 + c - 256]
                        : bv_s[l * 256 + c - 512];
    dst[idx] = v;
  } else {
    int j = idx - 3072;
    int l = j / 512, c = j - l * 512;
    float v = (c < 256) ? bk_c[l * 256 + c] : bv_c[l * 256 + c - 256];
    dst[idx] = v;
  }
}

// ---------------- bf16 MFMA GEMM: C = A(MxK,bf16) @ Wt(NxK,bf16)^T + bias ----
// global_load_lds(16B) staging, BK=64, linear LDS + XOR-swizzled source/read.
// tile 128x64, 4 waves (2x2), per-wave 4x2 16x16x32 frags, 16 MFMA/k-step.
// 1-D grid with XCD-chunked swizzle (nN arbitrary).
template<int ACT, int OBF>
__global__ __launch_bounds__(256, 3)
void gemm_bf(const __bf16* __restrict__ A, const __bf16* __restrict__ Bt,
             const float* __restrict__ bias, void* __restrict__ Cv,
             int N, int K, int nN, int ppx) {
  __shared__ __bf16 As[128 * 64];
  __shared__ __bf16 Bs[64 * 64];
  const int tid = threadIdx.x, lane = tid & 63, wv = tid >> 6;
  const int wm = (wv & 1) * 64, wn = (wv >> 1) * 32;
  const int ln15 = lane & 15, kgrp = lane >> 4;
  const int xcd = blockIdx.x & 7, j = blockIdx.x >> 3;
  const int bm = (xcd * ppx + j / nN) * 128;
  const int bn = (j % nN) * 64;

  // staging constants: lane covers (8-row group row8=lane>>3, 16B chunk c=lane&7)
  const int r8 = lane >> 3;
  const int scol = (lane & 7) ^ r8;                 // pre-swizzled source chunk
  const __bf16* a_g = A  + (size_t)(bm + wv * 32 + r8) * K + scol * 8;
  const __bf16* b_g = Bt + (size_t)(bn + wv * 16 + r8) * K + scol * 8;
  __bf16* a_l = As + wv * 2048;                     // wave LDS region (chunks*8)
  __bf16* b_l = Bs + wv * 1024;

  // frag read chunk-xor per kk half
  const int xk0 = kgrp ^ (ln15 & 7);
  const int xk1 = (4 + kgrp) ^ (ln15 & 7);

  f32x4_t acc[4][2];
#pragma unroll
  for (int mi = 0; mi < 4; ++mi)
#pragma unroll
    for (int ni = 0; ni < 2; ++ni) acc[mi][ni] = (f32x4_t){0.f, 0.f, 0.f, 0.f};

  for (int k0 = 0; k0 < K; k0 += 64) {
    gl16(a_g + k0,                a_l);
    gl16(a_g + k0 + (size_t)8*K,  a_l + 512);
    gl16(a_g + k0 + (size_t)16*K, a_l + 1024);
    gl16(a_g + k0 + (size_t)24*K, a_l + 1536);
    gl16(b_g + k0,                b_l);
    gl16(b_g + k0 + (size_t)8*K,  b_l + 512);
    __syncthreads();

#pragma unroll
    for (int kk = 0; kk < 2; ++kk) {
      const int xk = kk ? xk1 : xk0;
      bf16x8_t b0 = *(const bf16x8_t*)(Bs + ((wn + ln15) * 8 + xk) * 8);
      bf16x8_t b1 = *(const bf16x8_t*)(Bs + ((wn + 16 + ln15) * 8 + xk) * 8);
#pragma unroll
      for (int mi = 0; mi < 4; ++mi) {
        bf16x8_t af = *(const bf16x8_t*)(As + ((wm + mi * 16 + ln15) * 8 + xk) * 8);
        acc[mi][0] = __builtin_amdgcn_mfma_f32_16x16x32_bf16(af, b0, acc[mi][0], 0, 0, 0);
        acc[mi][1] = __builtin_amdgcn_mfma_f32_16x16x32_bf16(af, b1, acc[mi][1], 0, 0, 0);
      }
    }
    __syncthreads();
  }

#pragma unroll
  for (int mi = 0; mi < 4; ++mi) {
#pragma unroll
    for (int ni = 0; ni < 2; ++ni) {
      const int ocol = bn + wn + ni * 16 + ln15;
      const float bv = bias[ocol];
      const int orow0 = bm + wm + mi * 16 + kgrp * 4;
#pragma unroll
      for (int r = 0; r < 4; ++r) {
        float o = acc[mi][ni][r] + bv;
        if (ACT == 1) o = gelu_f(o);
        if (OBF) ((__bf16*)Cv)[(size_t)(orow0 + r) * N + ocol] = (__bf16)o;
        else     ((float*)Cv)[(size_t)(orow0 + r) * N + ocol] = o;
      }
    }
  }
}

// ---------------- MFMA flash attention (bf16 in, bf16 out) -------------------
// Q,K,V base pointers with row strides qs/ks (head slice h*HD_ applied inside).
// block = 4 waves; wave w owns q rows [qt*64 + w*16, +16); KV tiles of 32.
template<bool CAUSAL>
__global__ __launch_bounds__(256)
void attn_mfma(const __bf16* __restrict__ Q, const __bf16* __restrict__ K,
               const __bf16* __restrict__ V, __bf16* __restrict__ O,
               int KVROWS, int qs, int ks) {
  const int b = blockIdx.x >> 3, h = blockIdx.x & 7;
  const int qt = blockIdx.y;
  const int tid = threadIdx.x, lane = tid & 63, wv = tid >> 6;
  const int ln15 = lane & 15, kgrp = lane >> 4, kgrp8 = kgrp * 8;

  __shared__ __bf16 K_lds[32][40];
  __shared__ __bf16 Vt_lds[32][40];     // [hd][kv]
  __shared__ __bf16 P_lds[4][16][40];   // per-wave [q][kv]

  const int q_glob = qt * 64 + wv * 16 + ln15;
  const bf16x8_t qfrag = *(const bf16x8_t*)(Q + (size_t)(b * T_ + q_glob) * qs + h * HD_ + kgrp8);

  const int s_r = tid >> 3, s_c = (tid & 7) * 4;
  const __bf16* Kb = K + (size_t)(b * KVROWS + s_r) * ks + h * HD_ + s_c;
  const __bf16* Vb = V + (size_t)(b * KVROWS + s_r) * ks + h * HD_ + s_c;

  f32x4_t o0 = (f32x4_t){0.f,0.f,0.f,0.f}, o1 = (f32x4_t){0.f,0.f,0.f,0.f};
  float m = -3.0e38f, l = 0.f;
  const float SCALE = 0.17677669529663689f;
  const int slim = CAUSAL ? (qt + 1) * 64 : KVROWS;

  for (int s0 = 0; s0 < slim; s0 += 32) {
    *(uint2*)&K_lds[s_r][s_c] = *(const uint2*)(Kb + (size_t)s0 * ks);
    bf16x4_t vv = *(const bf16x4_t*)(Vb + (size_t)s0 * ks);
    Vt_lds[s_c + 0][s_r] = vv[0];
    Vt_lds[s_c + 1][s_r] = vv[1];
    Vt_lds[s_c + 2][s_r] = vv[2];
    Vt_lds[s_c + 3][s_r] = vv[3];
    __syncthreads();

    bf16x8_t kf0 = *(const bf16x8_t*)&K_lds[ln15][kgrp8];
    bf16x8_t kf1 = *(const bf16x8_t*)&K_lds[16 + ln15][kgrp8];
    f32x4_t sa0 = (f32x4_t){0.f,0.f,0.f,0.f}, sa1 = (f32x4_t){0.f,0.f,0.f,0.f};
    sa0 = __builtin_amdgcn_mfma_f32_16x16x32_bf16(kf0, qfrag, sa0, 0, 0, 0);
    sa1 = __builtin_amdgcn_mfma_f32_16x16x32_bf16(kf1, qfrag, sa1, 0, 0, 0);

    float v[8];
#pragma unroll
    for (int r = 0; r < 4; ++r) { v[r] = sa0[r] * SCALE; v[4 + r] = sa1[r] * SCALE; }
    if (CAUSAL) {
      const int sb = s0 + kgrp * 4;
#pragma unroll
      for (int r = 0; r < 4; ++r) {
        if (sb + r      > q_glob) v[r]     += -1e9f;
        if (sb + 16 + r > q_glob) v[4 + r] += -1e9f;
      }
    }
    float tmax = v[0];
#pragma unroll
    for (int r = 1; r < 8; ++r) tmax = fmaxf(tmax, v[r]);
    tmax = fmaxf(tmax, __shfl_xor(tmax, 16));
    tmax = fmaxf(tmax, __shfl_xor(tmax, 32));
    float mnew = fmaxf(m, tmax);
    float corr = __expf(m - mnew);

    float lsum = 0.f;
    bf16x4_t p0, p1;
#pragma unroll
    for (int r = 0; r < 4; ++r) {
      float e0 = __expf(v[r] - mnew);
      float e1 = __expf(v[4 + r] - mnew);
      lsum += e0 + e1;
      p0[r] = (__bf16)e0;
      p1[r] = (__bf16)e1;
    }
    *(bf16x4_t*)&P_lds[wv][ln15][kgrp * 4]      = p0;
    *(bf16x4_t*)&P_lds[wv][ln15][16 + kgrp * 4] = p1;
    lsum += __shfl_xor(lsum, 16);
    lsum += __shfl_xor(lsum, 32);
    l = l * corr + lsum;
    m = mnew;

    const float c0 = __shfl(corr, kgrp * 4 + 0);
    const float c1 = __shfl(corr, kgrp * 4 + 1);
    const float c2 = __shfl(corr, kgrp * 4 + 2);
    const float c3 = __shfl(corr, kgrp * 4 + 3);
    o0[0] *= c0; o0[1] *= c1; o0[2] *= c2; o0[3] *= c3;
    o1[0] *= c0; o1[1] *= c1; o1[2] *= c2; o1[3] *= c3;

    bf16x8_t pf  = *(const bf16x8_t*)&P_lds[wv][ln15][kgrp8];
    bf16x8_t vf0 = *(const bf16x8_t*)&Vt_lds[ln15][kgrp8];
    bf16x8_t vf1 = *(const bf16x8_t*)&Vt_lds[16 + ln15][kgrp8];
    o0 = __builtin_amdgcn_mfma_f32_16x16x32_bf16(pf, vf0, o0, 0, 0, 0);
    o1 = __builtin_amdgcn_mfma_f32_16x16x32_bf16(pf, vf1, o1, 0, 0, 0);
    __syncthreads();
  }

  const float inv = 1.f / l;
  const float i0 = __shfl(inv, kgrp * 4 + 0);
  const float i1 = __shfl(inv, kgrp * 4 + 1);
  const float i2 = __shfl(inv, kgrp * 4 + 2);
  const float i3 = __shfl(inv, kgrp * 4 + 3);
  __bf16* Op = O + (size_t)(b * T_ + qt * 64 + wv * 16 + kgrp * 4) * D_ + h * HD_;
  Op[0 * D_ + ln15] = (__bf16)(o0[0] * i0);  Op[0 * D_ + 16 + ln15] = (__bf16)(o1[0] * i0);
  Op[1 * D_ + ln15] = (__bf16)(o0[1] * i1);  Op[1 * D_ + 16 + ln15] = (__bf16)(o1[1] * i1);
  Op[2 * D_ + ln15] = (__bf16)(o0[2] * i2);  Op[2 * D_ + 16 + ln15] = (__bf16)(o1[2] * i2);
  Op[3 * D_ + ln15] = (__bf16)(o0[3] * i3);  Op[3 * D_ + 16 + ln15] = (__bf16)(o1[3] * i3);
}

// ------ fused residual add + LayerNorm (fp32 x in-place, + bf16 copy) --------
__global__ __launch_bounds__(256)
void add_ln_kernel(float* __restrict__ x, __bf16* __restrict__ xbf,
                   const float* __restrict__ y,
                   const float* __restrict__ g, const float* __restrict__ bta) {
  const int row = blockIdx.x * 4 + (threadIdx.x >> 6);
  const int lane = threadIdx.x & 63;
  const size_t base = (size_t)row * D_ + lane * 4;
  float4 xv = *(const float4*)&x[base];
  float4 yv = *(const float4*)&y[base];
  float v0 = xv.x + yv.x, v1 = xv.y + yv.y, v2 = xv.z + yv.z, v3 = xv.w + yv.w;
  float sum = v0 + v1 + v2 + v3;
  float sq  = v0 * v0 + v1 * v1 + v2 * v2 + v3 * v3;
#pragma unroll
  for (int off = 32; off; off >>= 1) {
    sum += __shfl_xor(sum, off);
    sq  += __shfl_xor(sq, off);
  }
  float mean = sum * (1.f / D_);
  float var  = sq * (1.f / D_) - mean * mean;
  float rstd = rsqrtf(fmaxf(var, 0.f) + 1e-5f);
  const int c = lane * 4;
  float4 gv = *(const float4*)&g[c];
  float4 bv = *(const float4*)&bta[c];
  float4 ov;
  ov.x = (v0 - mean) * rstd * gv.x + bv.x;
  ov.y = (v1 - mean) * rstd * gv.y + bv.y;
  ov.z = (v2 - mean) * rstd * gv.z + bv.z;
  ov.w = (v3 - mean) * rstd * gv.w + bv.w;
  *(float4*)&x[base] = ov;
  bf16x4_t ob;
  ob[0] = (__bf16)ov.x; ob[1] = (__bf16)ov.y; ob[2] = (__bf16)ov.z; ob[3] = (__bf16)ov.w;
  *(bf16x4_t*)&xbf[base] = ob;
}

// ---------------- final matvec: out = h(BTx128) @ Wp2(128x1) + bp2 -----------
__global__ __launch_bounds__(256)
void head2_kernel(const float* __restrict__ hb, const float* __restrict__ w,
                  const float* __restrict__ bias, float* __restrict__ out) {
  const int row = blockIdx.x * 4 + (threadIdx.x >> 6);
  const int lane = threadIdx.x & 63;
  float a = hb[(size_t)row * 128 + lane] * w[lane]
          + hb[(size_t)row * 128 + 64 + lane] * w[64 + lane];
#pragma unroll
  for (int off = 32; off; off >>= 1) a += __shfl_xor(a, off);
  if (lane == 0) out[row] = a + bias[0];
}

extern "C" void kernel_launch(void* const* d_in, const int* in_sizes, int n_in,
                              void* d_out, int out_size, void* d_ws, size_t ws_size,
                              hipStream_t stream) {
  const float* tgt    = (const float*)d_in[0];
  const float* memory = (const float*)d_in[1];
  const float* W_emb  = (const float*)d_in[2];
  const float* b_emb  = (const float*)d_in[3];
  const float* W_enc  = (const float*)d_in[4];
  const float* b_enc  = (const float*)d_in[5];
  const float* Wq_s = (const float*)d_in[6];  const float* bq_s = (const float*)d_in[7];
  const float* Wk_s = (const float*)d_in[8];  const float* bk_s = (const float*)d_in[9];
  const float* Wv_s = (const float*)d_in[10]; const float* bv_s = (const float*)d_in[11];
  const float* Wo_s = (const float*)d_in[12]; const float* bo_s = (const float*)d_in[13];
  const float* Wq_c = (const float*)d_in[14]; const float* bq_c = (const float*)d_in[15];
  const float* Wk_c = (const float*)d_in[16]; const float* bk_c = (const float*)d_in[17];
  const float* Wv_c = (const float*)d_in[18]; const float* bv_c = (const float*)d_in[19];
  const float* Wo_c = (const float*)d_in[20]; const float* bo_c = (const float*)d_in[21];
  const float* g1  = (const float*)d_in[22]; const float* be1 = (const float*)d_in[23];
  const float* g2  = (const float*)d_in[24]; const float* be2 = (const float*)d_in[25];
  const float* g3  = (const float*)d_in[26]; const float* be3 = (const float*)d_in[27];
  const float* Wf1 = (const float*)d_in[28]; const float* bf1 = (const float*)d_in[29];
  const float* Wf2 = (const float*)d_in[30]; const float* bf2 = (const float*)d_in[31];
  const float* Wp1 = (const float*)d_in[32]; const float* bp1 = (const float*)d_in[33];
  const float* Wp2 = (const float*)d_in[34]; const float* bp2 = (const float*)d_in[35];

  // ---- workspace layout (float units), ~97 MB total ----
  float*  x    = (float*)d_ws;                          // 4,194,304
  float*  y    = x + (size_t)BT_ * D_;                  // 4,194,304
  __bf16* xbf  = (__bf16*)(y + (size_t)BT_ * D_);       // BT*D bf16  (2,097,152 f)
  __bf16* membf= xbf + (size_t)BT_ * D_;                // BS*D bf16  (1,048,576 f)
  __bf16* qkv  = membf + (size_t)BS_ * D_;              // BT*768 bf16 (6,291,456 f)
  __bf16* ext  = qkv + (size_t)BT_ * 768;               // 4,194,304 bf16 (2,097,152 f)
  __bf16* ao   = ext + (size_t)4194304;                 // BT*D bf16 (2,097,152 f)
  __bf16* wt   = ao + (size_t)BT_ * D_;                 // 4,423,680 bf16 (2,211,840 f)
  float*  bcat = (float*)(wt + 4423680);                // 5,120 f
  // aliases (phase-disjoint):
  __bf16* memb = qkv;                                   // BS*ED bf16 (pre-layer only)
  __bf16* qc   = qkv;                                   // BT*D bf16 (cross phase)
  __bf16* kvc  = qkv + (size_t)BT_ * D_;                // BS*512 bf16 (cross phase)
  __bf16* ff   = qkv;                                   // BT*FF bf16 = qkv+ext exactly

  // bf16 weight region offsets (elements), [N][K] rows
  const size_t o_enc  = 0;         // 768*256? no: N=256 rows, K=768 -> 196608
  const size_t o_qkv  = 196608;    // 4 * (768*256) = 786432
  const size_t o_qcw  = 983040;    // 4 * 65536
  const size_t o_kvw  = 1245184;   // 4 * (512*256) = 524288
  const size_t o_os   = 1769472;   // 4 * 65536
  const size_t o_oc   = 2031616;   // 4 * 65536
  const size_t o_f1   = 2293760;   // 4 * 262144
  const size_t o_f2   = 3342336;   // 4 * 262144
  const size_t o_p1   = 4390912;   // 32768

  TDs td;
  td.d[0]  = {W_enc, o_enc,           ED_, D_,  1, 0};
  td.d[1]  = {Wq_s,  o_qkv + 0,       D_,  D_,  L_, 196608};
  td.d[2]  = {Wk_s,  o_qkv + 65536,   D_,  D_,  L_, 196608};
  td.d[3]  = {Wv_s,  o_qkv + 131072,  D_,  D_,  L_, 196608};
  td.d[4]  = {Wq_c,  o_qcw,           D_,  D_,  L_, 65536};
  td.d[5]  = {Wk_c,  o_kvw + 0,       D_,  D_,  L_, 131072};
  td.d[6]  = {Wv_c,  o_kvw + 65536,   D_,  D_,  L_, 131072};
  td.d[7]  = {Wo_s,  o_os,            D_,  D_,  L_, 65536};
  td.d[8]  = {Wo_c,  o_oc,            D_,  D_,  L_, 65536};
  td.d[9]  = {Wf1,   o_f1,            D_,  FF_, L_, 262144};
  td.d[10] = {Wf2,   o_f2,            FF_, D_,  L_, 262144};
  td.d[11] = {Wp1,   o_p1,            D_,  128, 1, 0};

  dim3 blk(256);
  cvt_bf16_kernel<<<BS_ * ED_ / 1024, blk, 0, stream>>>(memory, memb);
  transpose_cvt_kernel<<<dim3(1024, 12), blk, 0, stream>>>(td, wt);
  bias_concat_kernel<<<20, blk, 0, stream>>>(bq_s, bk_s, bv_s, bk_c, bv_c, bcat);
  embed_kernel<<<BT_ * D_ / 256, blk, 0, stream>>>(tgt, W_emb, b_emb, x, xbf);

  const float* bqkv = bcat;            // [L][768]
  const float* bkv  = bcat + 3072;     // [L][512]
  const dim3 gA(B_ * H_, T_ / 64);

  // encoder proj: mem(8192x768) -> membf(8192x256)
  gemm_bf<0,1><<<64 * 4, blk, 0, stream>>>(memb, wt + o_enc, b_enc, membf, D_, ED_, 4, 8);

  for (int i = 0; i < L_; ++i) {
    // ---- self attention ----
    gemm_bf<0,1><<<128 * 12, blk, 0, stream>>>(xbf, wt + o_qkv + (size_t)i * 196608, bqkv + i * 768, qkv, 768, D_, 12, 16);
    attn_mfma<true><<<gA, blk, 0, stream>>>(qkv, qkv + 256, qkv + 512, ao, T_, 768, 768);
    gemm_bf<0,0><<<128 * 4, blk, 0, stream>>>(ao, wt + o_os + (size_t)i * 65536, bo_s + i * D_, y, D_, D_, 4, 16);
    add_ln_kernel<<<BT_ / 4, blk, 0, stream>>>(x, xbf, y, g1 + i * D_, be1 + i * D_);
    // ---- cross attention ----
    gemm_bf<0,1><<<128 * 4, blk, 0, stream>>>(xbf, wt + o_qcw + (size_t)i * 65536, bq_c + i * D_, qc, D_, D_, 4, 16);
    gemm_bf<0,1><<<64 * 8, blk, 0, stream>>>(membf, wt + o_kvw + (size_t)i * 131072, bkv + i * 512, kvc, 512, D_, 8, 8);
    attn_mfma<false><<<gA, blk, 0, stream>>>(qc, kvc, kvc + 256, ao, S_, 256, 512);
    gemm_bf<0,0><<<128 * 4, blk, 0, stream>>>(ao, wt + o_oc + (size_t)i * 65536, bo_c + i * D_, y, D_, D_, 4, 16);
    add_ln_kernel<<<BT_ / 4, blk, 0, stream>>>(x, xbf, y, g2 + i * D_, be2 + i * D_);
    // ---- feed-forward ----
    gemm_bf<1,1><<<128 * 16, blk, 0, stream>>>(xbf, wt + o_f1 + (size_t)i * 262144, bf1 + i * FF_, ff, FF_, D_, 16, 16);
    gemm_bf<0,0><<<128 * 4, blk, 0, stream>>>(ff, wt + o_f2 + (size_t)i * 262144, bf2 + i * D_, y, D_, FF_, 4, 16);
    add_ln_kernel<<<BT_ / 4, blk, 0, stream>>>(x, xbf, y, g3 + i * D_, be3 + i * D_);
  }
  // ---- head ----
  gemm_bf<1,0><<<128 * 2, blk, 0, stream>>>(xbf, wt + o_p1, bp1, y, 128, D_, 2, 16);
  head2_kernel<<<BT_ / 4, blk, 0, stream>>>(y, Wp2, bp2, (float*)d_out);
}

// Round 6
// 710.907 us; speedup vs baseline: 4.3725x; 1.0583x over previous
//
#include <hip/hip_runtime.h>
#include <math.h>

#define B_  32
#define T_  512
#define S_  256
#define D_  256
#define H_  8
#define HD_ 32
#define FF_ 1024
#define ED_ 768
#define L_  4
#define BT_ (B_*T_)   // 16384
#define BS_ (B_*S_)   // 8192

typedef __bf16 bf16x8_t __attribute__((ext_vector_type(8)));
typedef __bf16 bf16x4_t __attribute__((ext_vector_type(4)));
typedef float  f32x4_t  __attribute__((ext_vector_type(4)));

__device__ __forceinline__ float gelu_f(float v) {
  return 0.5f * v * (1.f + erff(v * 0.7071067811865476f));
}

// async global->LDS, 16B per lane; LDS dest = uniform base + lane*16
__device__ __forceinline__ void gl16(const __bf16* gsrc, __bf16* ldst) {
  __builtin_amdgcn_global_load_lds(
      (const __attribute__((address_space(1))) unsigned int*)gsrc,
      (__attribute__((address_space(3))) unsigned int*)ldst, 16, 0, 0);
}

// ---------------- embed: x = tgt*W_emb + b_emb + pos_encoding ----------------
__global__ __launch_bounds__(256)
void embed_kernel(const float* __restrict__ tgt, const float* __restrict__ Wemb,
                  const float* __restrict__ bemb, float* __restrict__ x,
                  __bf16* __restrict__ xbf) {
  int i = blockIdx.x * 256 + threadIdx.x;
  int d  = i & (D_ - 1);
  int bt = i >> 8;
  int t  = bt & (T_ - 1);
  int p  = d >> 1;
  float div = expf((float)(2 * p) * (-9.210340371976184f / (float)D_));
  float arg = (float)t * div;
  float pe = (d & 1) ? cosf(arg) : sinf(arg);
  float v = tgt[bt] * Wemb[d] + bemb[d] + pe;
  x[i] = v;
  xbf[i] = (__bf16)v;
}

// ---------------- fp32 -> bf16 bulk convert ----------------------------------
__global__ __launch_bounds__(256)
void cvt_bf16_kernel(const float* __restrict__ in, __bf16* __restrict__ out) {
  int i = (blockIdx.x * 256 + threadIdx.x) * 4;
  float4 v = *(const float4*)(in + i);
  bf16x4_t o;
  o[0] = (__bf16)v.x; o[1] = (__bf16)v.y; o[2] = (__bf16)v.z; o[3] = (__bf16)v.w;
  *(bf16x4_t*)(out + i) = o;
}

// ------------- weight pre-pass: transpose [K][N] fp32 -> [N][K] bf16 ---------
struct TD { const float* src; size_t dst; int K, N, nb; size_t lstride; };
struct TDs { TD d[12]; };

__global__ __launch_bounds__(256)
void transpose_cvt_kernel(TDs a, __bf16* __restrict__ wt) {
  __shared__ float tile[32][33];
  TD t = a.d[blockIdx.y];
  const int kt = t.K >> 5, nt = t.N >> 5;
  const int per = kt * nt, tot = per * t.nb;
  const int id = blockIdx.x;
  if (id >= tot) return;
  const int b = id / per;
  const int r2 = id - b * per;
  const int kti = r2 / nt;
  const int nti = r2 - kti * nt;
  const int c = threadIdx.x & 31, r0 = threadIdx.x >> 5;
  const float* src = t.src + (size_t)b * t.K * t.N;
  __bf16* dst = wt + t.dst + (size_t)b * t.lstride;
#pragma unroll
  for (int j = 0; j < 4; ++j) {
    int rr = r0 + j * 8;
    tile[rr][c] = src[(size_t)(kti * 32 + rr) * t.N + nti * 32 + c];
  }
  __syncthreads();
#pragma unroll
  for (int j = 0; j < 4; ++j) {
    int rr = r0 + j * 8;
    dst[(size_t)(nti * 32 + rr) * t.K + kti * 32 + c] = (__bf16)tile[c][rr];
  }
}

// ---------------- concat biases: [L][768] self-qkv, then [L][512] cross-kv ---
__global__ __launch_bounds__(256)
void bias_concat_kernel(const float* __restrict__ bq_s, const float* __restrict__ bk_s,
                        const float* __restrict__ bv_s, const float* __restrict__ bk_c,
                        const float* __restrict__ bv_c, float* __restrict__ dst) {
  int idx = blockIdx.x * 256 + threadIdx.x;
  if (idx >= 5120) return;
  if (idx < 3072) {
    int l = idx / 768, c = idx - l * 768;
    float v = (c < 256) ? bq_s[l * 256 + c]
            : (c < 512) ? bk_s[l * 256 + c - 256]
                        : bv_s[l * 256 + c - 512];
    dst[idx] = v;
  } else {
    int j = idx - 3072;
    int l = j / 512, c = j - l * 512;
    float v = (c < 256) ? bk_c[l * 256 + c] : bv_c[l * 256 + c - 256];
    dst[idx] = v;
  }
}

// ------------- bf16 MFMA GEMM, tile 128x64 (for N=256-class shapes) ----------
// global_load_lds(16B) staging, BK=64, linear LDS + XOR-swizzled source/read.
template<int ACT, int OBF>
__global__ __launch_bounds__(256, 3)
void gemm_bf(const __bf16* __restrict__ A, const __bf16* __restrict__ Bt,
             const float* __restrict__ bias, void* __restrict__ Cv,
             int N, int K, int nN, int ppx) {
  __shared__ __bf16 As[128 * 64];
  __shared__ __bf16 Bs[64 * 64];
  const int tid = threadIdx.x, lane = tid & 63, wv = tid >> 6;
  const int wm = (wv & 1) * 64, wn = (wv >> 1) * 32;
  const int ln15 = lane & 15, kgrp = lane >> 4;
  const int xcd = blockIdx.x & 7, j = blockIdx.x >> 3;
  const int bm = (xcd * ppx + j / nN) * 128;
  const int bn = (j % nN) * 64;

  const int r8 = lane >> 3;
  const int scol = (lane & 7) ^ r8;                 // pre-swizzled source chunk
  const __bf16* a_g = A  + (size_t)(bm + wv * 32 + r8) * K + scol * 8;
  const __bf16* b_g = Bt + (size_t)(bn + wv * 16 + r8) * K + scol * 8;
  __bf16* a_l = As + wv * 2048;
  __bf16* b_l = Bs + wv * 1024;

  const int xk0 = kgrp ^ (ln15 & 7);
  const int xk1 = (4 + kgrp) ^ (ln15 & 7);

  f32x4_t acc[4][2];
#pragma unroll
  for (int mi = 0; mi < 4; ++mi)
#pragma unroll
    for (int ni = 0; ni < 2; ++ni) acc[mi][ni] = (f32x4_t){0.f, 0.f, 0.f, 0.f};

  for (int k0 = 0; k0 < K; k0 += 64) {
    gl16(a_g + k0,                a_l);
    gl16(a_g + k0 + (size_t)8*K,  a_l + 512);
    gl16(a_g + k0 + (size_t)16*K, a_l + 1024);
    gl16(a_g + k0 + (size_t)24*K, a_l + 1536);
    gl16(b_g + k0,                b_l);
    gl16(b_g + k0 + (size_t)8*K,  b_l + 512);
    __syncthreads();

#pragma unroll
    for (int kk = 0; kk < 2; ++kk) {
      const int xk = kk ? xk1 : xk0;
      bf16x8_t b0 = *(const bf16x8_t*)(Bs + ((wn + ln15) * 8 + xk) * 8);
      bf16x8_t b1 = *(const bf16x8_t*)(Bs + ((wn + 16 + ln15) * 8 + xk) * 8);
#pragma unroll
      for (int mi = 0; mi < 4; ++mi) {
        bf16x8_t af = *(const bf16x8_t*)(As + ((wm + mi * 16 + ln15) * 8 + xk) * 8);
        acc[mi][0] = __builtin_amdgcn_mfma_f32_16x16x32_bf16(af, b0, acc[mi][0], 0, 0, 0);
        acc[mi][1] = __builtin_amdgcn_mfma_f32_16x16x32_bf16(af, b1, acc[mi][1], 0, 0, 0);
      }
    }
    __syncthreads();
  }

#pragma unroll
  for (int mi = 0; mi < 4; ++mi) {
#pragma unroll
    for (int ni = 0; ni < 2; ++ni) {
      const int ocol = bn + wn + ni * 16 + ln15;
      const float bv = bias[ocol];
      const int orow0 = bm + wm + mi * 16 + kgrp * 4;
#pragma unroll
      for (int r = 0; r < 4; ++r) {
        float o = acc[mi][ni][r] + bv;
        if (ACT == 1) o = gelu_f(o);
        if (OBF) ((__bf16*)Cv)[(size_t)(orow0 + r) * N + ocol] = (__bf16)o;
        else     ((float*)Cv)[(size_t)(orow0 + r) * N + ocol] = o;
      }
    }
  }
}

// ------------- bf16 MFMA GEMM, tile 128x128 (wide-N: QKV, FF1) ---------------
// 4 waves (2x2), per-wave 64x64 = 4x4 frags; 16 ds_read per 32 MFMA per K-step.
template<int ACT, int OBF>
__global__ __launch_bounds__(256, 3)
void gemm_bf2(const __bf16* __restrict__ A, const __bf16* __restrict__ Bt,
              const float* __restrict__ bias, void* __restrict__ Cv,
              int N, int K, int nN, int ppx) {
  __shared__ __bf16 As[128 * 64];
  __shared__ __bf16 Bs[128 * 64];
  const int tid = threadIdx.x, lane = tid & 63, wv = tid >> 6;
  const int wm = (wv & 1) * 64, wn = (wv >> 1) * 64;
  const int ln15 = lane & 15, kgrp = lane >> 4;
  const int xcd = blockIdx.x & 7, j = blockIdx.x >> 3;
  const int bm = (xcd * ppx + j / nN) * 128;
  const int bn = (j % nN) * 128;

  const int r8 = lane >> 3;
  const int scol = (lane & 7) ^ r8;
  const __bf16* a_g = A  + (size_t)(bm + wv * 32 + r8) * K + scol * 8;
  const __bf16* b_g = Bt + (size_t)(bn + wv * 32 + r8) * K + scol * 8;
  __bf16* a_l = As + wv * 2048;
  __bf16* b_l = Bs + wv * 2048;

  const int xk0 = kgrp ^ (ln15 & 7);
  const int xk1 = (4 + kgrp) ^ (ln15 & 7);

  f32x4_t acc[4][4];
#pragma unroll
  for (int mi = 0; mi < 4; ++mi)
#pragma unroll
    for (int ni = 0; ni < 4; ++ni) acc[mi][ni] = (f32x4_t){0.f, 0.f, 0.f, 0.f};

  for (int k0 = 0; k0 < K; k0 += 64) {
    gl16(a_g + k0,                a_l);
    gl16(a_g + k0 + (size_t)8*K,  a_l + 512);
    gl16(a_g + k0 + (size_t)16*K, a_l + 1024);
    gl16(a_g + k0 + (size_t)24*K, a_l + 1536);
    gl16(b_g + k0,                b_l);
    gl16(b_g + k0 + (size_t)8*K,  b_l + 512);
    gl16(b_g + k0 + (size_t)16*K, b_l + 1024);
    gl16(b_g + k0 + (size_t)24*K, b_l + 1536);
    __syncthreads();

#pragma unroll
    for (int kk = 0; kk < 2; ++kk) {
      const int xk = kk ? xk1 : xk0;
      bf16x8_t bfr[4];
#pragma unroll
      for (int ni = 0; ni < 4; ++ni)
        bfr[ni] = *(const bf16x8_t*)(Bs + ((wn + ni * 16 + ln15) * 8 + xk) * 8);
#pragma unroll
      for (int mi = 0; mi < 4; ++mi) {
        bf16x8_t af = *(const bf16x8_t*)(As + ((wm + mi * 16 + ln15) * 8 + xk) * 8);
#pragma unroll
        for (int ni = 0; ni < 4; ++ni)
          acc[mi][ni] = __builtin_amdgcn_mfma_f32_16x16x32_bf16(af, bfr[ni], acc[mi][ni], 0, 0, 0);
      }
    }
    __syncthreads();
  }

#pragma unroll
  for (int mi = 0; mi < 4; ++mi) {
#pragma unroll
    for (int ni = 0; ni < 4; ++ni) {
      const int ocol = bn + wn + ni * 16 + ln15;
      const float bv = bias[ocol];
      const int orow0 = bm + wm + mi * 16 + kgrp * 4;
#pragma unroll
      for (int r = 0; r < 4; ++r) {
        float o = acc[mi][ni][r] + bv;
        if (ACT == 1) o = gelu_f(o);
        if (OBF) ((__bf16*)Cv)[(size_t)(orow0 + r) * N + ocol] = (__bf16)o;
        else     ((float*)Cv)[(size_t)(orow0 + r) * N + ocol] = o;
      }
    }
  }
}

// ---------------- MFMA flash attention (bf16 in, bf16 out), KVBLK=64 ---------
// block = 4 waves; wave w owns q rows [qt*64 + w*16, +16).
// Swapped QK^T: mfma(A=K_tile, B=Q) -> lane holds S[kv=c*16+kgrp*4+r][q=ln15].
template<bool CAUSAL>
__global__ __launch_bounds__(256)
void attn_mfma(const __bf16* __restrict__ Q, const __bf16* __restrict__ K,
               const __bf16* __restrict__ V, __bf16* __restrict__ O,
               int KVROWS, int qs, int ks) {
  const int b = blockIdx.x >> 3, h = blockIdx.x & 7;
  const int qt = blockIdx.y;
  const int tid = threadIdx.x, lane = tid & 63, wv = tid >> 6;
  const int ln15 = lane & 15, kgrp = lane >> 4, kgrp8 = kgrp * 8;

  __shared__ __bf16 K_lds[64][36];
  __shared__ __bf16 Vt_lds[32][72];     // [hd][kv]
  __shared__ __bf16 P_lds[4][16][72];   // per-wave [q][kv]

  const int q_glob = qt * 64 + wv * 16 + ln15;
  const bf16x8_t qfrag = *(const bf16x8_t*)(Q + (size_t)(b * T_ + q_glob) * qs + h * HD_ + kgrp8);

  const int s_r = tid >> 2, s_c8 = (tid & 3) * 8;     // 64 rows x 8-elem hd chunks
  const __bf16* Kb = K + (size_t)(b * KVROWS + s_r) * ks + h * HD_ + s_c8;
  const __bf16* Vb = V + (size_t)(b * KVROWS + s_r) * ks + h * HD_ + s_c8;

  f32x4_t o0 = (f32x4_t){0.f,0.f,0.f,0.f}, o1 = (f32x4_t){0.f,0.f,0.f,0.f};
  float m = -3.0e38f, l = 0.f;
  const float SCALE = 0.17677669529663689f;
  const int slim = CAUSAL ? (qt + 1) * 64 : KVROWS;

  for (int s0 = 0; s0 < slim; s0 += 64) {
    *(bf16x8_t*)&K_lds[s_r][s_c8] = *(const bf16x8_t*)(Kb + (size_t)s0 * ks);
    bf16x8_t vv = *(const bf16x8_t*)(Vb + (size_t)s0 * ks);
#pragma unroll
    for (int jj = 0; jj < 8; ++jj) Vt_lds[s_c8 + jj][s_r] = vv[jj];
    __syncthreads();

    // ---- S^T = K_tile(64) @ Q^T : four 16-row subtiles ----
    f32x4_t sa[4];
#pragma unroll
    for (int c = 0; c < 4; ++c) {
      bf16x8_t kf = *(const bf16x8_t*)&K_lds[c * 16 + ln15][kgrp8];
      sa[c] = __builtin_amdgcn_mfma_f32_16x16x32_bf16(kf, qfrag, (f32x4_t){0.f,0.f,0.f,0.f}, 0, 0, 0);
    }
    float v[16];
#pragma unroll
    for (int c = 0; c < 4; ++c)
#pragma unroll
      for (int r = 0; r < 4; ++r) {
        float s = sa[c][r] * SCALE;
        if (CAUSAL && (s0 + c * 16 + kgrp * 4 + r) > q_glob) s += -1e9f;
        v[c * 4 + r] = s;
      }
    float tmax = v[0];
#pragma unroll
    for (int r = 1; r < 16; ++r) tmax = fmaxf(tmax, v[r]);
    tmax = fmaxf(tmax, __shfl_xor(tmax, 16));
    tmax = fmaxf(tmax, __shfl_xor(tmax, 32));
    float mnew = fmaxf(m, tmax);
    float corr = __expf(m - mnew);

    float lsum = 0.f;
#pragma unroll
    for (int c = 0; c < 4; ++c) {
      bf16x4_t pc;
#pragma unroll
      for (int r = 0; r < 4; ++r) {
        float e = __expf(v[c * 4 + r] - mnew);
        lsum += e;
        pc[r] = (__bf16)e;
      }
      *(bf16x4_t*)&P_lds[wv][ln15][c * 16 + kgrp * 4] = pc;
    }
    lsum += __shfl_xor(lsum, 16);
    lsum += __shfl_xor(lsum, 32);
    l = l * corr + lsum;
    m = mnew;

    // ---- rescale O (q = kgrp*4 + reg) ----
    const float c0 = __shfl(corr, kgrp * 4 + 0);
    const float c1 = __shfl(corr, kgrp * 4 + 1);
    const float c2 = __shfl(corr, kgrp * 4 + 2);
    const float c3 = __shfl(corr, kgrp * 4 + 3);
    o0[0] *= c0; o0[1] *= c1; o0[2] *= c2; o0[3] *= c3;
    o1[0] *= c0; o1[1] *= c1; o1[2] *= c2; o1[3] *= c3;

    // ---- PV: O[q][hd] += P(16x64) @ V(64x32) ----
    bf16x8_t pLo = *(const bf16x8_t*)&P_lds[wv][ln15][kgrp8];
    bf16x8_t pHi = *(const bf16x8_t*)&P_lds[wv][ln15][32 + kgrp8];
    bf16x8_t v0l = *(const bf16x8_t*)&Vt_lds[ln15][kgrp8];
    bf16x8_t v0h = *(const bf16x8_t*)&Vt_lds[ln15][32 + kgrp8];
    bf16x8_t v1l = *(const bf16x8_t*)&Vt_lds[16 + ln15][kgrp8];
    bf16x8_t v1h = *(const bf16x8_t*)&Vt_lds[16 + ln15][32 + kgrp8];
    o0 = __builtin_amdgcn_mfma_f32_16x16x32_bf16(pLo, v0l, o0, 0, 0, 0);
    o0 = __builtin_amdgcn_mfma_f32_16x16x32_bf16(pHi, v0h, o0, 0, 0, 0);
    o1 = __builtin_amdgcn_mfma_f32_16x16x32_bf16(pLo, v1l, o1, 0, 0, 0);
    o1 = __builtin_amdgcn_mfma_f32_16x16x32_bf16(pHi, v1h, o1, 0, 0, 0);
    __syncthreads();
  }

  const float inv = 1.f / l;
  const float i0 = __shfl(inv, kgrp * 4 + 0);
  const float i1 = __shfl(inv, kgrp * 4 + 1);
  const float i2 = __shfl(inv, kgrp * 4 + 2);
  const float i3 = __shfl(inv, kgrp * 4 + 3);
  __bf16* Op = O + (size_t)(b * T_ + qt * 64 + wv * 16 + kgrp * 4) * D_ + h * HD_;
  Op[0 * D_ + ln15] = (__bf16)(o0[0] * i0);  Op[0 * D_ + 16 + ln15] = (__bf16)(o1[0] * i0);
  Op[1 * D_ + ln15] = (__bf16)(o0[1] * i1);  Op[1 * D_ + 16 + ln15] = (__bf16)(o1[1] * i1);
  Op[2 * D_ + ln15] = (__bf16)(o0[2] * i2);  Op[2 * D_ + 16 + ln15] = (__bf16)(o1[2] * i2);
  Op[3 * D_ + ln15] = (__bf16)(o0[3] * i3);  Op[3 * D_ + 16 + ln15] = (__bf16)(o1[3] * i3);
}

// ------ fused residual add + LayerNorm (fp32 x in-place, + bf16 copy) --------
__global__ __launch_bounds__(256)
void add_ln_kernel(float* __restrict__ x, __bf16* __restrict__ xbf,
                   const __bf16* __restrict__ y,
                   const float* __restrict__ g, const float* __restrict__ bta) {
  const int row = blockIdx.x * 4 + (threadIdx.x >> 6);
  const int lane = threadIdx.x & 63;
  const size_t base = (size_t)row * D_ + lane * 4;
  float4 xv = *(const float4*)&x[base];
  bf16x4_t yv = *(const bf16x4_t*)&y[base];
  float v0 = xv.x + (float)yv[0], v1 = xv.y + (float)yv[1];
  float v2 = xv.z + (float)yv[2], v3 = xv.w + (float)yv[3];
  float sum = v0 + v1 + v2 + v3;
  float sq  = v0 * v0 + v1 * v1 + v2 * v2 + v3 * v3;
#pragma unroll
  for (int off = 32; off; off >>= 1) {
    sum += __shfl_xor(sum, off);
    sq  += __shfl_xor(sq, off);
  }
  float mean = sum * (1.f / D_);
  float var  = sq * (1.f / D_) - mean * mean;
  float rstd = rsqrtf(fmaxf(var, 0.f) + 1e-5f);
  const int c = lane * 4;
  float4 gv = *(const float4*)&g[c];
  float4 bv = *(const float4*)&bta[c];
  float4 ov;
  ov.x = (v0 - mean) * rstd * gv.x + bv.x;
  ov.y = (v1 - mean) * rstd * gv.y + bv.y;
  ov.z = (v2 - mean) * rstd * gv.z + bv.z;
  ov.w = (v3 - mean) * rstd * gv.w + bv.w;
  *(float4*)&x[base] = ov;
  bf16x4_t ob;
  ob[0] = (__bf16)ov.x; ob[1] = (__bf16)ov.y; ob[2] = (__bf16)ov.z; ob[3] = (__bf16)ov.w;
  *(bf16x4_t*)&xbf[base] = ob;
}

// ---------------- final matvec: out = h(BTx128) @ Wp2(128x1) + bp2 -----------
__global__ __launch_bounds__(256)
void head2_kernel(const float* __restrict__ hb, const float* __restrict__ w,
                  const float* __restrict__ bias, float* __restrict__ out) {
  const int row = blockIdx.x * 4 + (threadIdx.x >> 6);
  const int lane = threadIdx.x & 63;
  float a = hb[(size_t)row * 128 + lane] * w[lane]
          + hb[(size_t)row * 128 + 64 + lane] * w[64 + lane];
#pragma unroll
  for (int off = 32; off; off >>= 1) a += __shfl_xor(a, off);
  if (lane == 0) out[row] = a + bias[0];
}

extern "C" void kernel_launch(void* const* d_in, const int* in_sizes, int n_in,
                              void* d_out, int out_size, void* d_ws, size_t ws_size,
                              hipStream_t stream) {
  const float* tgt    = (const float*)d_in[0];
  const float* memory = (const float*)d_in[1];
  const float* W_emb  = (const float*)d_in[2];
  const float* b_emb  = (const float*)d_in[3];
  const float* W_enc  = (const float*)d_in[4];
  const float* b_enc  = (const float*)d_in[5];
  const float* Wq_s = (const float*)d_in[6];  const float* bq_s = (const float*)d_in[7];
  const float* Wk_s = (const float*)d_in[8];  const float* bk_s = (const float*)d_in[9];
  const float* Wv_s = (const float*)d_in[10]; const float* bv_s = (const float*)d_in[11];
  const float* Wo_s = (const float*)d_in[12]; const float* bo_s = (const float*)d_in[13];
  const float* Wq_c = (const float*)d_in[14]; const float* bq_c = (const float*)d_in[15];
  const float* Wk_c = (const float*)d_in[16]; const float* bk_c = (const float*)d_in[17];
  const float* Wv_c = (const float*)d_in[18]; const float* bv_c = (const float*)d_in[19];
  const float* Wo_c = (const float*)d_in[20]; const float* bo_c = (const float*)d_in[21];
  const float* g1  = (const float*)d_in[22]; const float* be1 = (const float*)d_in[23];
  const float* g2  = (const float*)d_in[24]; const float* be2 = (const float*)d_in[25];
  const float* g3  = (const float*)d_in[26]; const float* be3 = (const float*)d_in[27];
  const float* Wf1 = (const float*)d_in[28]; const float* bf1 = (const float*)d_in[29];
  const float* Wf2 = (const float*)d_in[30]; const float* bf2 = (const float*)d_in[31];
  const float* Wp1 = (const float*)d_in[32]; const float* bp1 = (const float*)d_in[33];
  const float* Wp2 = (const float*)d_in[34]; const float* bp2 = (const float*)d_in[35];

  // ---- workspace layout (float units) ----
  float*  x    = (float*)d_ws;                          // 4,194,304
  float*  yf   = x + (size_t)BT_ * D_;                  // 4,194,304 (f32 head / bf16 y)
  __bf16* ybf  = (__bf16*)yf;
  __bf16* xbf  = (__bf16*)(yf + (size_t)BT_ * D_);      // BT*D bf16
  __bf16* membf= xbf + (size_t)BT_ * D_;                // BS*D bf16
  __bf16* qkv  = membf + (size_t)BS_ * D_;              // BT*768 bf16
  __bf16* ext  = qkv + (size_t)BT_ * 768;               // 4,194,304 bf16
  __bf16* ao   = ext + (size_t)4194304;                 // BT*D bf16
  __bf16* wt   = ao + (size_t)BT_ * D_;                 // 4,423,680 bf16
  float*  bcat = (float*)(wt + 4423680);                // 5,120 f
  // aliases (phase-disjoint):
  __bf16* memb = qkv;
  __bf16* qc   = qkv;
  __bf16* kvc  = qkv + (size_t)BT_ * D_;
  __bf16* ff   = qkv;                                   // BT*FF = qkv+ext exactly

  const size_t o_enc  = 0;
  const size_t o_qkv  = 196608;
  const size_t o_qcw  = 983040;
  const size_t o_kvw  = 1245184;
  const size_t o_os   = 1769472;
  const size_t o_oc   = 2031616;
  const size_t o_f1   = 2293760;
  const size_t o_f2   = 3342336;
  const size_t o_p1   = 4390912;

  TDs td;
  td.d[0]  = {W_enc, o_enc,           ED_, D_,  1, 0};
  td.d[1]  = {Wq_s,  o_qkv + 0,       D_,  D_,  L_, 196608};
  td.d[2]  = {Wk_s,  o_qkv + 65536,   D_,  D_,  L_, 196608};
  td.d[3]  = {Wv_s,  o_qkv + 131072,  D_,  D_,  L_, 196608};
  td.d[4]  = {Wq_c,  o_qcw,           D_,  D_,  L_, 65536};
  td.d[5]  = {Wk_c,  o_kvw + 0,       D_,  D_,  L_, 131072};
  td.d[6]  = {Wv_c,  o_kvw + 65536,   D_,  D_,  L_, 131072};
  td.d[7]  = {Wo_s,  o_os,            D_,  D_,  L_, 65536};
  td.d[8]  = {Wo_c,  o_oc,            D_,  D_,  L_, 65536};
  td.d[9]  = {Wf1,   o_f1,            D_,  FF_, L_, 262144};
  td.d[10] = {Wf2,   o_f2,            FF_, D_,  L_, 262144};
  td.d[11] = {Wp1,   o_p1,            D_,  128, 1, 0};

  dim3 blk(256);
  cvt_bf16_kernel<<<BS_ * ED_ / 1024, blk, 0, stream>>>(memory, memb);
  transpose_cvt_kernel<<<dim3(1024, 12), blk, 0, stream>>>(td, wt);
  bias_concat_kernel<<<20, blk, 0, stream>>>(bq_s, bk_s, bv_s, bk_c, bv_c, bcat);
  embed_kernel<<<BT_ * D_ / 256, blk, 0, stream>>>(tgt, W_emb, b_emb, x, xbf);

  const float* bqkv = bcat;            // [L][768]
  const float* bkv  = bcat + 3072;     // [L][512]
  const dim3 gA(B_ * H_, T_ / 64);

  // encoder proj: mem(8192x768) -> membf(8192x256)
  gemm_bf<0,1><<<64 * 4, blk, 0, stream>>>(memb, wt + o_enc, b_enc, membf, D_, ED_, 4, 8);

  for (int i = 0; i < L_; ++i) {
    // ---- self attention ----
    gemm_bf2<0,1><<<128 * 6, blk, 0, stream>>>(xbf, wt + o_qkv + (size_t)i * 196608, bqkv + i * 768, qkv, 768, D_, 6, 16);
    attn_mfma<true><<<gA, blk, 0, stream>>>(qkv, qkv + 256, qkv + 512, ao, T_, 768, 768);
    gemm_bf<0,1><<<128 * 4, blk, 0, stream>>>(ao, wt + o_os + (size_t)i * 65536, bo_s + i * D_, ybf, D_, D_, 4, 16);
    add_ln_kernel<<<BT_ / 4, blk, 0, stream>>>(x, xbf, ybf, g1 + i * D_, be1 + i * D_);
    // ---- cross attention ----
    gemm_bf<0,1><<<128 * 4, blk, 0, stream>>>(xbf, wt + o_qcw + (size_t)i * 65536, bq_c + i * D_, qc, D_, D_, 4, 16);
    gemm_bf<0,1><<<64 * 8, blk, 0, stream>>>(membf, wt + o_kvw + (size_t)i * 131072, bkv + i * 512, kvc, 512, D_, 8, 8);
    attn_mfma<false><<<gA, blk, 0, stream>>>(qc, kvc, kvc + 256, ao, S_, 256, 512);
    gemm_bf<0,1><<<128 * 4, blk, 0, stream>>>(ao, wt + o_oc + (size_t)i * 65536, bo_c + i * D_, ybf, D_, D_, 4, 16);
    add_ln_kernel<<<BT_ / 4, blk, 0, stream>>>(x, xbf, ybf, g2 + i * D_, be2 + i * D_);
    // ---- feed-forward ----
    gemm_bf2<1,1><<<128 * 8, blk, 0, stream>>>(xbf, wt + o_f1 + (size_t)i * 262144, bf1 + i * FF_, ff, FF_, D_, 8, 16);
    gemm_bf<0,1><<<128 * 4, blk, 0, stream>>>(ff, wt + o_f2 + (size_t)i * 262144, bf2 + i * D_, ybf, D_, FF_, 4, 16);
    add_ln_kernel<<<BT_ / 4, blk, 0, stream>>>(x, xbf, ybf, g3 + i * D_, be3 + i * D_);
  }
  // ---- head ----
  gemm_bf<1,0><<<128 * 2, blk, 0, stream>>>(xbf, wt + o_p1, bp1, yf, 128, D_, 2, 16);
  head2_kernel<<<BT_ / 4, blk, 0, stream>>>(yf, Wp2, bp2, (float*)d_out);
}

// Round 7
// 697.426 us; speedup vs baseline: 4.4570x; 1.0193x over previous
//
#include <hip/hip_runtime.h>
#include <math.h>

#define B_  32
#define T_  512
#define S_  256
#define D_  256
#define H_  8
#define HD_ 32
#define FF_ 1024
#define ED_ 768
#define L_  4
#define BT_ (B_*T_)   // 16384
#define BS_ (B_*S_)   // 8192

typedef __bf16 bf16x8_t __attribute__((ext_vector_type(8)));
typedef __bf16 bf16x4_t __attribute__((ext_vector_type(4)));
typedef float  f32x4_t  __attribute__((ext_vector_type(4)));

__device__ __forceinline__ float gelu_f(float v) {
  return 0.5f * v * (1.f + erff(v * 0.7071067811865476f));
}

// async global->LDS, 16B per lane; LDS dest = wave-uniform base + lane*16
__device__ __forceinline__ void gl16(const __bf16* gsrc, __bf16* ldst) {
  __builtin_amdgcn_global_load_lds(
      (const __attribute__((address_space(1))) unsigned int*)gsrc,
      (__attribute__((address_space(3))) unsigned int*)ldst, 16, 0, 0);
}

// ---------------- embed: x = tgt*W_emb + b_emb + pos_encoding ----------------
__global__ __launch_bounds__(256)
void embed_kernel(const float* __restrict__ tgt, const float* __restrict__ Wemb,
                  const float* __restrict__ bemb, float* __restrict__ x,
                  __bf16* __restrict__ xbf) {
  int i = blockIdx.x * 256 + threadIdx.x;
  int d  = i & (D_ - 1);
  int bt = i >> 8;
  int t  = bt & (T_ - 1);
  int p  = d >> 1;
  float div = expf((float)(2 * p) * (-9.210340371976184f / (float)D_));
  float arg = (float)t * div;
  float pe = (d & 1) ? cosf(arg) : sinf(arg);
  float v = tgt[bt] * Wemb[d] + bemb[d] + pe;
  x[i] = v;
  xbf[i] = (__bf16)v;
}

// ---------------- fp32 -> bf16 bulk convert ----------------------------------
__global__ __launch_bounds__(256)
void cvt_bf16_kernel(const float* __restrict__ in, __bf16* __restrict__ out) {
  int i = (blockIdx.x * 256 + threadIdx.x) * 4;
  float4 v = *(const float4*)(in + i);
  bf16x4_t o;
  o[0] = (__bf16)v.x; o[1] = (__bf16)v.y; o[2] = (__bf16)v.z; o[3] = (__bf16)v.w;
  *(bf16x4_t*)(out + i) = o;
}

// ------------- weight pre-pass: transpose [K][N] fp32 -> [N][K] bf16 ---------
struct TD { const float* src; size_t dst; int K, N, nb; size_t lstride; };
struct TDs { TD d[12]; };

__global__ __launch_bounds__(256)
void transpose_cvt_kernel(TDs a, __bf16* __restrict__ wt) {
  __shared__ float tile[32][33];
  TD t = a.d[blockIdx.y];
  const int kt = t.K >> 5, nt = t.N >> 5;
  const int per = kt * nt, tot = per * t.nb;
  const int id = blockIdx.x;
  if (id >= tot) return;
  const int b = id / per;
  const int r2 = id - b * per;
  const int kti = r2 / nt;
  const int nti = r2 - kti * nt;
  const int c = threadIdx.x & 31, r0 = threadIdx.x >> 5;
  const float* src = t.src + (size_t)b * t.K * t.N;
  __bf16* dst = wt + t.dst + (size_t)b * t.lstride;
#pragma unroll
  for (int j = 0; j < 4; ++j) {
    int rr = r0 + j * 8;
    tile[rr][c] = src[(size_t)(kti * 32 + rr) * t.N + nti * 32 + c];
  }
  __syncthreads();
#pragma unroll
  for (int j = 0; j < 4; ++j) {
    int rr = r0 + j * 8;
    dst[(size_t)(nti * 32 + rr) * t.K + kti * 32 + c] = (__bf16)tile[c][rr];
  }
}

// ---------------- concat biases: [L][768] self-qkv, then [L][512] cross-kv ---
__global__ __launch_bounds__(256)
void bias_concat_kernel(const float* __restrict__ bq_s, const float* __restrict__ bk_s,
                        const float* __restrict__ bv_s, const float* __restrict__ bk_c,
                        const float* __restrict__ bv_c, float* __restrict__ dst) {
  int idx = blockIdx.x * 256 + threadIdx.x;
  if (idx >= 5120) return;
  if (idx < 3072) {
    int l = idx / 768, c = idx - l * 768;
    float v = (c < 256) ? bq_s[l * 256 + c]
            : (c < 512) ? bk_s[l * 256 + c - 256]
                        : bv_s[l * 256 + c - 512];
    dst[idx] = v;
  } else {
    int j = idx - 3072;
    int l = j / 512, c = j - l * 512;
    float v = (c < 256) ? bk_c[l * 256 + c] : bv_c[l * 256 + c - 256];
    dst[idx] = v;
  }
}

// ------------- bf16 MFMA GEMM, tile 128x64 ----------------------------------
template<int ACT, int OBF>
__global__ __launch_bounds__(256, 3)
void gemm_bf(const __bf16* __restrict__ A, const __bf16* __restrict__ Bt,
             const float* __restrict__ bias, void* __restrict__ Cv,
             int N, int K, int nN, int ppx) {
  __shared__ __bf16 As[128 * 64];
  __shared__ __bf16 Bs[64 * 64];
  const int tid = threadIdx.x, lane = tid & 63, wv = tid >> 6;
  const int wm = (wv & 1) * 64, wn = (wv >> 1) * 32;
  const int ln15 = lane & 15, kgrp = lane >> 4;
  const int xcd = blockIdx.x & 7, j = blockIdx.x >> 3;
  const int bm = (xcd * ppx + j / nN) * 128;
  const int bn = (j % nN) * 64;

  const int r8 = lane >> 3;
  const int scol = (lane & 7) ^ r8;
  const __bf16* a_g = A  + (size_t)(bm + wv * 32 + r8) * K + scol * 8;
  const __bf16* b_g = Bt + (size_t)(bn + wv * 16 + r8) * K + scol * 8;
  __bf16* a_l = As + wv * 2048;
  __bf16* b_l = Bs + wv * 1024;

  const int xk0 = kgrp ^ (ln15 & 7);
  const int xk1 = (4 + kgrp) ^ (ln15 & 7);

  f32x4_t acc[4][2];
#pragma unroll
  for (int mi = 0; mi < 4; ++mi)
#pragma unroll
    for (int ni = 0; ni < 2; ++ni) acc[mi][ni] = (f32x4_t){0.f, 0.f, 0.f, 0.f};

  for (int k0 = 0; k0 < K; k0 += 64) {
    gl16(a_g + k0,                a_l);
    gl16(a_g + k0 + (size_t)8*K,  a_l + 512);
    gl16(a_g + k0 + (size_t)16*K, a_l + 1024);
    gl16(a_g + k0 + (size_t)24*K, a_l + 1536);
    gl16(b_g + k0,                b_l);
    gl16(b_g + k0 + (size_t)8*K,  b_l + 512);
    __syncthreads();

#pragma unroll
    for (int kk = 0; kk < 2; ++kk) {
      const int xk = kk ? xk1 : xk0;
      bf16x8_t b0 = *(const bf16x8_t*)(Bs + ((wn + ln15) * 8 + xk) * 8);
      bf16x8_t b1 = *(const bf16x8_t*)(Bs + ((wn + 16 + ln15) * 8 + xk) * 8);
#pragma unroll
      for (int mi = 0; mi < 4; ++mi) {
        bf16x8_t af = *(const bf16x8_t*)(As + ((wm + mi * 16 + ln15) * 8 + xk) * 8);
        acc[mi][0] = __builtin_amdgcn_mfma_f32_16x16x32_bf16(af, b0, acc[mi][0], 0, 0, 0);
        acc[mi][1] = __builtin_amdgcn_mfma_f32_16x16x32_bf16(af, b1, acc[mi][1], 0, 0, 0);
      }
    }
    __syncthreads();
  }

#pragma unroll
  for (int mi = 0; mi < 4; ++mi) {
#pragma unroll
    for (int ni = 0; ni < 2; ++ni) {
      const int ocol = bn + wn + ni * 16 + ln15;
      const float bv = bias[ocol];
      const int orow0 = bm + wm + mi * 16 + kgrp * 4;
#pragma unroll
      for (int r = 0; r < 4; ++r) {
        float o = acc[mi][ni][r] + bv;
        if (ACT == 1) o = gelu_f(o);
        if (OBF) ((__bf16*)Cv)[(size_t)(orow0 + r) * N + ocol] = (__bf16)o;
        else     ((float*)Cv)[(size_t)(orow0 + r) * N + ocol] = o;
      }
    }
  }
}

// ------------- bf16 MFMA GEMM, tile 128x128 (wide-N: QKV, FF1, KVall) --------
template<int ACT, int OBF>
__global__ __launch_bounds__(256, 3)
void gemm_bf2(const __bf16* __restrict__ A, const __bf16* __restrict__ Bt,
              const float* __restrict__ bias, void* __restrict__ Cv,
              int N, int K, int nN, int ppx) {
  __shared__ __bf16 As[128 * 64];
  __shared__ __bf16 Bs[128 * 64];
  const int tid = threadIdx.x, lane = tid & 63, wv = tid >> 6;
  const int wm = (wv & 1) * 64, wn = (wv >> 1) * 64;
  const int ln15 = lane & 15, kgrp = lane >> 4;
  const int xcd = blockIdx.x & 7, j = blockIdx.x >> 3;
  const int bm = (xcd * ppx + j / nN) * 128;
  const int bn = (j % nN) * 128;

  const int r8 = lane >> 3;
  const int scol = (lane & 7) ^ r8;
  const __bf16* a_g = A  + (size_t)(bm + wv * 32 + r8) * K + scol * 8;
  const __bf16* b_g = Bt + (size_t)(bn + wv * 32 + r8) * K + scol * 8;
  __bf16* a_l = As + wv * 2048;
  __bf16* b_l = Bs + wv * 2048;

  const int xk0 = kgrp ^ (ln15 & 7);
  const int xk1 = (4 + kgrp) ^ (ln15 & 7);

  f32x4_t acc[4][4];
#pragma unroll
  for (int mi = 0; mi < 4; ++mi)
#pragma unroll
    for (int ni = 0; ni < 4; ++ni) acc[mi][ni] = (f32x4_t){0.f, 0.f, 0.f, 0.f};

  for (int k0 = 0; k0 < K; k0 += 64) {
    gl16(a_g + k0,                a_l);
    gl16(a_g + k0 + (size_t)8*K,  a_l + 512);
    gl16(a_g + k0 + (size_t)16*K, a_l + 1024);
    gl16(a_g + k0 + (size_t)24*K, a_l + 1536);
    gl16(b_g + k0,                b_l);
    gl16(b_g + k0 + (size_t)8*K,  b_l + 512);
    gl16(b_g + k0 + (size_t)16*K, b_l + 1024);
    gl16(b_g + k0 + (size_t)24*K, b_l + 1536);
    __syncthreads();

#pragma unroll
    for (int kk = 0; kk < 2; ++kk) {
      const int xk = kk ? xk1 : xk0;
      bf16x8_t bfr[4];
#pragma unroll
      for (int ni = 0; ni < 4; ++ni)
        bfr[ni] = *(const bf16x8_t*)(Bs + ((wn + ni * 16 + ln15) * 8 + xk) * 8);
#pragma unroll
      for (int mi = 0; mi < 4; ++mi) {
        bf16x8_t af = *(const bf16x8_t*)(As + ((wm + mi * 16 + ln15) * 8 + xk) * 8);
#pragma unroll
        for (int ni = 0; ni < 4; ++ni)
          acc[mi][ni] = __builtin_amdgcn_mfma_f32_16x16x32_bf16(af, bfr[ni], acc[mi][ni], 0, 0, 0);
      }
    }
    __syncthreads();
  }

#pragma unroll
  for (int mi = 0; mi < 4; ++mi) {
#pragma unroll
    for (int ni = 0; ni < 4; ++ni) {
      const int ocol = bn + wn + ni * 16 + ln15;
      const float bv = bias[ocol];
      const int orow0 = bm + wm + mi * 16 + kgrp * 4;
#pragma unroll
      for (int r = 0; r < 4; ++r) {
        float o = acc[mi][ni][r] + bv;
        if (ACT == 1) o = gelu_f(o);
        if (OBF) ((__bf16*)Cv)[(size_t)(orow0 + r) * N + ocol] = (__bf16)o;
        else     ((float*)Cv)[(size_t)(orow0 + r) * N + ocol] = o;
      }
    }
  }
}

// ------ fused GEMM(64x256 tile) + residual + LayerNorm ----------------------
// y = A@Bt^T + bias; x = LN(x + y)*g + bta  (x fp32 in-place, xbf bf16 copy)
// 512 thr = 8 waves (2M x 4N); per-wave 32x64 = 2x4 frags. N fixed = 256.
__global__ __launch_bounds__(512)
void gemm_ln(const __bf16* __restrict__ A, const __bf16* __restrict__ Bt,
             const float* __restrict__ bias, const float* __restrict__ g,
             const float* __restrict__ bta, float* __restrict__ x,
             __bf16* __restrict__ xbf, int K, int ppx) {
  __shared__ __bf16 As[64 * 64];
  __shared__ __bf16 Bs[256 * 64];
  __shared__ float red[64][8];
  const int tid = threadIdx.x, lane = tid & 63, wv = tid >> 6;
  const int wm = (wv >> 2) * 32, wn = (wv & 3) * 64;
  const int ln15 = lane & 15, kgrp = lane >> 4;
  const int xcd = blockIdx.x & 7, j = blockIdx.x >> 3;
  const int bm = (xcd * ppx + j) * 64;

  const int sr = tid >> 3;                      // 0..63
  const int sch = (tid & 7) ^ (sr & 7);         // pre-swizzled source chunk
  const __bf16* a_g = A  + (size_t)(bm + sr) * K + sch * 8;
  const __bf16* b_g = Bt + (size_t)sr * K + sch * 8;
  __bf16* a_l = As + wv * 512;
  __bf16* b_l = Bs + wv * 512;

  const int xk0 = kgrp ^ (ln15 & 7);
  const int xk1 = (4 + kgrp) ^ (ln15 & 7);

  f32x4_t acc[2][4];
#pragma unroll
  for (int mi = 0; mi < 2; ++mi)
#pragma unroll
    for (int ni = 0; ni < 4; ++ni) acc[mi][ni] = (f32x4_t){0.f, 0.f, 0.f, 0.f};

  for (int k0 = 0; k0 < K; k0 += 64) {
    gl16(a_g + k0,                 a_l);
    gl16(b_g + k0,                 b_l);
    gl16(b_g + k0 + (size_t)64*K,  b_l + 4096);
    gl16(b_g + k0 + (size_t)128*K, b_l + 8192);
    gl16(b_g + k0 + (size_t)192*K, b_l + 12288);
    __syncthreads();

#pragma unroll
    for (int kk = 0; kk < 2; ++kk) {
      const int xk = kk ? xk1 : xk0;
      bf16x8_t bfr[4];
#pragma unroll
      for (int ni = 0; ni < 4; ++ni)
        bfr[ni] = *(const bf16x8_t*)(Bs + ((wn + ni * 16 + ln15) * 8 + xk) * 8);
#pragma unroll
      for (int mi = 0; mi < 2; ++mi) {
        bf16x8_t af = *(const bf16x8_t*)(As + ((wm + mi * 16 + ln15) * 8 + xk) * 8);
#pragma unroll
        for (int ni = 0; ni < 4; ++ni)
          acc[mi][ni] = __builtin_amdgcn_mfma_f32_16x16x32_bf16(af, bfr[ni], acc[mi][ni], 0, 0, 0);
      }
    }
    __syncthreads();
  }

  // ---- epilogue: residual + LN over 256 cols ----
  const int c0 = wn + ln15;
  float bs[4], gg[4], bb[4];
#pragma unroll
  for (int ni = 0; ni < 4; ++ni) {
    bs[ni] = bias[c0 + ni * 16];
    gg[ni] = g[c0 + ni * 16];
    bb[ni] = bta[c0 + ni * 16];
  }
  float v[2][4][4];
#pragma unroll
  for (int mi = 0; mi < 2; ++mi) {
#pragma unroll
    for (int r = 0; r < 4; ++r) {
      const int row = bm + wm + mi * 16 + kgrp * 4 + r;
      float s = 0.f, q = 0.f;
#pragma unroll
      for (int ni = 0; ni < 4; ++ni) {
        float t = acc[mi][ni][r] + bs[ni] + x[(size_t)row * 256 + c0 + ni * 16];
        v[mi][ni][r] = t; s += t; q += t * t;
      }
      s += __shfl_xor(s, 1); s += __shfl_xor(s, 2);
      s += __shfl_xor(s, 4); s += __shfl_xor(s, 8);
      q += __shfl_xor(q, 1); q += __shfl_xor(q, 2);
      q += __shfl_xor(q, 4); q += __shfl_xor(q, 8);
      if (ln15 == 0) {
        red[wm + mi * 16 + kgrp * 4 + r][(wv & 3) * 2 + 0] = s;
        red[wm + mi * 16 + kgrp * 4 + r][(wv & 3) * 2 + 1] = q;
      }
    }
  }
  __syncthreads();
#pragma unroll
  for (int mi = 0; mi < 2; ++mi) {
#pragma unroll
    for (int r = 0; r < 4; ++r) {
      const int rl = wm + mi * 16 + kgrp * 4 + r;
      const int row = bm + rl;
      const float ms = red[rl][0] + red[rl][2] + red[rl][4] + red[rl][6];
      const float mq = red[rl][1] + red[rl][3] + red[rl][5] + red[rl][7];
      const float mean = ms * (1.f / 256.f);
      const float var  = mq * (1.f / 256.f) - mean * mean;
      const float rstd = rsqrtf(fmaxf(var, 0.f) + 1e-5f);
#pragma unroll
      for (int ni = 0; ni < 4; ++ni) {
        float o = (v[mi][ni][r] - mean) * rstd * gg[ni] + bb[ni];
        x[(size_t)row * 256 + c0 + ni * 16] = o;
        xbf[(size_t)row * 256 + c0 + ni * 16] = (__bf16)o;
      }
    }
  }
}

// ---------------- MFMA flash attention (bf16 in, bf16 out), KVBLK=64 ---------
template<bool CAUSAL>
__global__ __launch_bounds__(256)
void attn_mfma(const __bf16* __restrict__ Q, const __bf16* __restrict__ K,
               const __bf16* __restrict__ V, __bf16* __restrict__ O,
               int KVROWS, int qs, int ks) {
  const int b = blockIdx.x >> 3, h = blockIdx.x & 7;
  const int qt = blockIdx.y;
  const int tid = threadIdx.x, lane = tid & 63, wv = tid >> 6;
  const int ln15 = lane & 15, kgrp = lane >> 4, kgrp8 = kgrp * 8;

  __shared__ __bf16 K_lds[64][36];
  __shared__ __bf16 Vt_lds[32][72];
  __shared__ __bf16 P_lds[4][16][72];

  const int q_glob = qt * 64 + wv * 16 + ln15;
  const bf16x8_t qfrag = *(const bf16x8_t*)(Q + (size_t)(b * T_ + q_glob) * qs + h * HD_ + kgrp8);

  const int s_r = tid >> 2, s_c8 = (tid & 3) * 8;
  const __bf16* Kb = K + (size_t)(b * KVROWS + s_r) * ks + h * HD_ + s_c8;
  const __bf16* Vb = V + (size_t)(b * KVROWS + s_r) * ks + h * HD_ + s_c8;

  f32x4_t o0 = (f32x4_t){0.f,0.f,0.f,0.f}, o1 = (f32x4_t){0.f,0.f,0.f,0.f};
  float m = -3.0e38f, l = 0.f;
  const float SCALE = 0.17677669529663689f;
  const int slim = CAUSAL ? (qt + 1) * 64 : KVROWS;

  for (int s0 = 0; s0 < slim; s0 += 64) {
    *(bf16x8_t*)&K_lds[s_r][s_c8] = *(const bf16x8_t*)(Kb + (size_t)s0 * ks);
    bf16x8_t vv = *(const bf16x8_t*)(Vb + (size_t)s0 * ks);
#pragma unroll
    for (int jj = 0; jj < 8; ++jj) Vt_lds[s_c8 + jj][s_r] = vv[jj];
    __syncthreads();

    f32x4_t sa[4];
#pragma unroll
    for (int c = 0; c < 4; ++c) {
      bf16x8_t kf = *(const bf16x8_t*)&K_lds[c * 16 + ln15][kgrp8];
      sa[c] = __builtin_amdgcn_mfma_f32_16x16x32_bf16(kf, qfrag, (f32x4_t){0.f,0.f,0.f,0.f}, 0, 0, 0);
    }
    float v[16];
#pragma unroll
    for (int c = 0; c < 4; ++c)
#pragma unroll
      for (int r = 0; r < 4; ++r) {
        float s = sa[c][r] * SCALE;
        if (CAUSAL && (s0 + c * 16 + kgrp * 4 + r) > q_glob) s += -1e9f;
        v[c * 4 + r] = s;
      }
    float tmax = v[0];
#pragma unroll
    for (int r = 1; r < 16; ++r) tmax = fmaxf(tmax, v[r]);
    tmax = fmaxf(tmax, __shfl_xor(tmax, 16));
    tmax = fmaxf(tmax, __shfl_xor(tmax, 32));
    float mnew = fmaxf(m, tmax);
    float corr = __expf(m - mnew);

    float lsum = 0.f;
#pragma unroll
    for (int c = 0; c < 4; ++c) {
      bf16x4_t pc;
#pragma unroll
      for (int r = 0; r < 4; ++r) {
        float e = __expf(v[c * 4 + r] - mnew);
        lsum += e;
        pc[r] = (__bf16)e;
      }
      *(bf16x4_t*)&P_lds[wv][ln15][c * 16 + kgrp * 4] = pc;
    }
    lsum += __shfl_xor(lsum, 16);
    lsum += __shfl_xor(lsum, 32);
    l = l * corr + lsum;
    m = mnew;

    const float c0 = __shfl(corr, kgrp * 4 + 0);
    const float c1 = __shfl(corr, kgrp * 4 + 1);
    const float c2 = __shfl(corr, kgrp * 4 + 2);
    const float c3 = __shfl(corr, kgrp * 4 + 3);
    o0[0] *= c0; o0[1] *= c1; o0[2] *= c2; o0[3] *= c3;
    o1[0] *= c0; o1[1] *= c1; o1[2] *= c2; o1[3] *= c3;

    bf16x8_t pLo = *(const bf16x8_t*)&P_lds[wv][ln15][kgrp8];
    bf16x8_t pHi = *(const bf16x8_t*)&P_lds[wv][ln15][32 + kgrp8];
    bf16x8_t v0l = *(const bf16x8_t*)&Vt_lds[ln15][kgrp8];
    bf16x8_t v0h = *(const bf16x8_t*)&Vt_lds[ln15][32 + kgrp8];
    bf16x8_t v1l = *(const bf16x8_t*)&Vt_lds[16 + ln15][kgrp8];
    bf16x8_t v1h = *(const bf16x8_t*)&Vt_lds[16 + ln15][32 + kgrp8];
    o0 = __builtin_amdgcn_mfma_f32_16x16x32_bf16(pLo, v0l, o0, 0, 0, 0);
    o0 = __builtin_amdgcn_mfma_f32_16x16x32_bf16(pHi, v0h, o0, 0, 0, 0);
    o1 = __builtin_amdgcn_mfma_f32_16x16x32_bf16(pLo, v1l, o1, 0, 0, 0);
    o1 = __builtin_amdgcn_mfma_f32_16x16x32_bf16(pHi, v1h, o1, 0, 0, 0);
    __syncthreads();
  }

  const float inv = 1.f / l;
  const float i0 = __shfl(inv, kgrp * 4 + 0);
  const float i1 = __shfl(inv, kgrp * 4 + 1);
  const float i2 = __shfl(inv, kgrp * 4 + 2);
  const float i3 = __shfl(inv, kgrp * 4 + 3);
  __bf16* Op = O + (size_t)(b * T_ + qt * 64 + wv * 16 + kgrp * 4) * D_ + h * HD_;
  Op[0 * D_ + ln15] = (__bf16)(o0[0] * i0);  Op[0 * D_ + 16 + ln15] = (__bf16)(o1[0] * i0);
  Op[1 * D_ + ln15] = (__bf16)(o0[1] * i1);  Op[1 * D_ + 16 + ln15] = (__bf16)(o1[1] * i1);
  Op[2 * D_ + ln15] = (__bf16)(o0[2] * i2);  Op[2 * D_ + 16 + ln15] = (__bf16)(o1[2] * i2);
  Op[3 * D_ + ln15] = (__bf16)(o0[3] * i3);  Op[3 * D_ + 16 + ln15] = (__bf16)(o1[3] * i3);
}

// ---------------- final matvec: out = h(BTx128) @ Wp2(128x1) + bp2 -----------
__global__ __launch_bounds__(256)
void head2_kernel(const float* __restrict__ hb, const float* __restrict__ w,
                  const float* __restrict__ bias, float* __restrict__ out) {
  const int row = blockIdx.x * 4 + (threadIdx.x >> 6);
  const int lane = threadIdx.x & 63;
  float a = hb[(size_t)row * 128 + lane] * w[lane]
          + hb[(size_t)row * 128 + 64 + lane] * w[64 + lane];
#pragma unroll
  for (int off = 32; off; off >>= 1) a += __shfl_xor(a, off);
  if (lane == 0) out[row] = a + bias[0];
}

extern "C" void kernel_launch(void* const* d_in, const int* in_sizes, int n_in,
                              void* d_out, int out_size, void* d_ws, size_t ws_size,
                              hipStream_t stream) {
  const float* tgt    = (const float*)d_in[0];
  const float* memory = (const float*)d_in[1];
  const float* W_emb  = (const float*)d_in[2];
  const float* b_emb  = (const float*)d_in[3];
  const float* W_enc  = (const float*)d_in[4];
  const float* b_enc  = (const float*)d_in[5];
  const float* Wq_s = (const float*)d_in[6];  const float* bq_s = (const float*)d_in[7];
  const float* Wk_s = (const float*)d_in[8];  const float* bk_s = (const float*)d_in[9];
  const float* Wv_s = (const float*)d_in[10]; const float* bv_s = (const float*)d_in[11];
  const float* Wo_s = (const float*)d_in[12]; const float* bo_s = (const float*)d_in[13];
  const float* Wq_c = (const float*)d_in[14]; const float* bq_c = (const float*)d_in[15];
  const float* Wk_c = (const float*)d_in[16]; const float* bk_c = (const float*)d_in[17];
  const float* Wv_c = (const float*)d_in[18]; const float* bv_c = (const float*)d_in[19];
  const float* Wo_c = (const float*)d_in[20]; const float* bo_c = (const float*)d_in[21];
  const float* g1  = (const float*)d_in[22]; const float* be1 = (const float*)d_in[23];
  const float* g2  = (const float*)d_in[24]; const float* be2 = (const float*)d_in[25];
  const float* g3  = (const float*)d_in[26]; const float* be3 = (const float*)d_in[27];
  const float* Wf1 = (const float*)d_in[28]; const float* bf1 = (const float*)d_in[29];
  const float* Wf2 = (const float*)d_in[30]; const float* bf2 = (const float*)d_in[31];
  const float* Wp1 = (const float*)d_in[32]; const float* bp1 = (const float*)d_in[33];
  const float* Wp2 = (const float*)d_in[34]; const float* bp2 = (const float*)d_in[35];

  // ---- workspace layout (float units), ~114 MB total ----
  float*  x     = (float*)d_ws;                             // 4,194,304
  __bf16* xbf   = (__bf16*)(x + (size_t)4194304);           // 2,097,152 f
  __bf16* membf = xbf + (size_t)4194304;                    // 1,048,576 f
  __bf16* wt    = (__bf16*)((float*)membf + 1048576);       // 2,211,840 f
  float*  bcat  = (float*)(wt + 4423680);                   // 8,192 f
  __bf16* kvall = (__bf16*)(bcat + 8192);                   // 8,388,608 f (8192x2048)
  __bf16* scr   = kvall + (size_t)16777216;                 // 8,388,608 f
  __bf16* ao    = scr + (size_t)16777216;                   // 2,097,152 f
  // aliases (phase-disjoint) inside scr:
  __bf16* memb = scr;                                       // BS*ED bf16 (pre-layer)
  __bf16* qkv  = scr;                                       // BT*768 bf16 (self phase)
  __bf16* qc   = scr;                                       // BT*D bf16 (cross phase)
  __bf16* ff   = scr;                                       // BT*FF bf16 (ff phase)
  float*  hbuf = (float*)ao;                                // BT*128 f32 (head phase)

  const size_t o_enc  = 0;
  const size_t o_qkv  = 196608;
  const size_t o_qcw  = 983040;
  const size_t o_kvw  = 1245184;
  const size_t o_os   = 1769472;
  const size_t o_oc   = 2031616;
  const size_t o_f1   = 2293760;
  const size_t o_f2   = 3342336;
  const size_t o_p1   = 4390912;

  TDs td;
  td.d[0]  = {W_enc, o_enc,           ED_, D_,  1, 0};
  td.d[1]  = {Wq_s,  o_qkv + 0,       D_,  D_,  L_, 196608};
  td.d[2]  = {Wk_s,  o_qkv + 65536,   D_,  D_,  L_, 196608};
  td.d[3]  = {Wv_s,  o_qkv + 131072,  D_,  D_,  L_, 196608};
  td.d[4]  = {Wq_c,  o_qcw,           D_,  D_,  L_, 65536};
  td.d[5]  = {Wk_c,  o_kvw + 0,       D_,  D_,  L_, 131072};
  td.d[6]  = {Wv_c,  o_kvw + 65536,   D_,  D_,  L_, 131072};
  td.d[7]  = {Wo_s,  o_os,            D_,  D_,  L_, 65536};
  td.d[8]  = {Wo_c,  o_oc,            D_,  D_,  L_, 65536};
  td.d[9]  = {Wf1,   o_f1,            D_,  FF_, L_, 262144};
  td.d[10] = {Wf2,   o_f2,            FF_, D_,  L_, 262144};
  td.d[11] = {Wp1,   o_p1,            D_,  128, 1, 0};

  dim3 blk(256);
  cvt_bf16_kernel<<<BS_ * ED_ / 1024, blk, 0, stream>>>(memory, memb);
  transpose_cvt_kernel<<<dim3(1024, 12), blk, 0, stream>>>(td, wt);
  bias_concat_kernel<<<20, blk, 0, stream>>>(bq_s, bk_s, bv_s, bk_c, bv_c, bcat);
  embed_kernel<<<BT_ * D_ / 256, blk, 0, stream>>>(tgt, W_emb, b_emb, x, xbf);

  const float* bqkv = bcat;            // [L][768]
  const float* bkv  = bcat + 3072;     // [L*512] = linear for combined GEMM
  const dim3 gA(B_ * H_, T_ / 64);

  // encoder proj: memb(8192x768) -> membf(8192x256)
  gemm_bf<0,1><<<64 * 4, blk, 0, stream>>>(memb, wt + o_enc, b_enc, membf, D_, ED_, 4, 8);
  // ALL layers' cross-KV: membf(8192x256) @ [2048x256]^T -> kvall(8192x2048)
  gemm_bf2<0,1><<<64 * 16, blk, 0, stream>>>(membf, wt + o_kvw, bkv, kvall, 2048, D_, 16, 8);

  for (int i = 0; i < L_; ++i) {
    // ---- self attention ----
    gemm_bf2<0,1><<<128 * 6, blk, 0, stream>>>(xbf, wt + o_qkv + (size_t)i * 196608, bqkv + i * 768, qkv, 768, D_, 6, 16);
    attn_mfma<true><<<gA, blk, 0, stream>>>(qkv, qkv + 256, qkv + 512, ao, T_, 768, 768);
    gemm_ln<<<256, dim3(512), 0, stream>>>(ao, wt + o_os + (size_t)i * 65536, bo_s + i * D_,
                                           g1 + i * D_, be1 + i * D_, x, xbf, D_, 32);
    // ---- cross attention ----
    gemm_bf<0,1><<<128 * 4, blk, 0, stream>>>(xbf, wt + o_qcw + (size_t)i * 65536, bq_c + i * D_, qc, D_, D_, 4, 16);
    attn_mfma<false><<<gA, blk, 0, stream>>>(qc, kvall + i * 512, kvall + i * 512 + 256, ao, S_, 256, 2048);
    gemm_ln<<<256, dim3(512), 0, stream>>>(ao, wt + o_oc + (size_t)i * 65536, bo_c + i * D_,
                                           g2 + i * D_, be2 + i * D_, x, xbf, D_, 32);
    // ---- feed-forward ----
    gemm_bf2<1,1><<<128 * 8, blk, 0, stream>>>(xbf, wt + o_f1 + (size_t)i * 262144, bf1 + i * FF_, ff, FF_, D_, 8, 16);
    gemm_ln<<<256, dim3(512), 0, stream>>>(ff, wt + o_f2 + (size_t)i * 262144, bf2 + i * D_,
                                           g3 + i * D_, be3 + i * D_, x, xbf, FF_, 32);
  }
  // ---- head ----
  gemm_bf<1,0><<<128 * 2, blk, 0, stream>>>(xbf, wt + o_p1, bp1, hbuf, 128, D_, 2, 16);
  head2_kernel<<<BT_ / 4, blk, 0, stream>>>(hbuf, Wp2, bp2, (float*)d_out);
}